// Round 1
// 340.785 us; speedup vs baseline: 1.0075x; 1.0075x over previous
//
#include <hip/hip_runtime.h>
#include <hip/hip_bf16.h>

// Problem constants (B=1)
#define T_SEQ 2048
#define D_MODEL 2048
#define NH 16
#define HDIM 128
#define RD_ROT 64

typedef __bf16 bf16x8 __attribute__((ext_vector_type(8)));
typedef float f32x4 __attribute__((ext_vector_type(4)));

__device__ __forceinline__ void async_copy16(const __bf16* g, __bf16* l) {
    __builtin_amdgcn_global_load_lds(
        (const __attribute__((address_space(1))) void*)g,
        (__attribute__((address_space(3))) void*)l, 16, 0, 0);
}

// ---------------------------------------------------------------------------
// Cast fp32 -> bf16 for the 5 GEMM operands (hidden, Wq, Wk, Wv, Wo).
// ---------------------------------------------------------------------------
__global__ __launch_bounds__(256) void cast_kernel(
    const float* __restrict__ s0, const float* __restrict__ s1, const float* __restrict__ s2,
    const float* __restrict__ s3, const float* __restrict__ s4,
    __bf16* __restrict__ d0, __bf16* __restrict__ d1, __bf16* __restrict__ d2,
    __bf16* __restrict__ d3, __bf16* __restrict__ d4)
{
    const float* s; __bf16* d;
    switch (blockIdx.y) {
        case 0: s = s0; d = d0; break;
        case 1: s = s1; d = d1; break;
        case 2: s = s2; d = d2; break;
        case 3: s = s3; d = d3; break;
        default: s = s4; d = d4; break;
    }
    size_t base = (size_t)blockIdx.x * D_MODEL + (size_t)threadIdx.x * 8;
    f32x4 a = *(const f32x4*)(s + base);
    f32x4 b = *(const f32x4*)(s + base + 4);
    bf16x8 o;
    #pragma unroll
    for (int i = 0; i < 4; i++) { o[i] = (__bf16)a[i]; o[i + 4] = (__bf16)b[i]; }
    *(bf16x8*)(d + base) = o;
}

// ---------------------------------------------------------------------------
// LDS fragment read: rows are 64 bf16 = 128 B = exactly 32 banks, so a naive
// column read is a 16-way conflict. st_16x32-style swizzle: 16B chunk index
// XORed with (row & 7) -> 2-way max (free). Write side is pre-swizzled on the
// GLOBAL source address (global_load_lds dest must stay linear).
// ---------------------------------------------------------------------------
__device__ __forceinline__ bf16x8 ld_frag(const __bf16* lds, int rr, int s, int quad, int r7) {
    return *(const bf16x8*)&lds[rr * 64 + ((((s << 2) + quad) ^ r7) << 3)];
}

// ---------------------------------------------------------------------------
// QKV GEMM: C = A @ B^T, 256x256 tile, BK=64, 512 threads (8 waves, 2M x 4N),
// 4 phases per K-tile with counted vmcnt (T3+T4), T2 XOR swizzle, T5 setprio,
// T1 XCD-swizzled grid. Schedule (per K-tile t, buf b = t&1):
//   ph1: ds_read A(M0)+B(N0) (12xb128) | bar | lgkm0 | 16 MFMA M0N0 | bar
//   ph2: ds_read A(M1)+B(N1) (12xb128) | bar | lgkm0 | 16 MFMA M1N1 | bar
//   ph3: stage A-half0+B-half0 of t+2 -> buf b | bar | 16 MFMA M0N1 | bar
//   ph4: stage A-half1+B-half1 of t+2 -> buf b | bar | 16 MFMA M1N0 |
//        vmcnt(8) (drains t+1's loads, issued 5 phases ago; t+2's 8 stay in
//        flight across the barrier) | bar
// Region safety: all reads of buf b retire at ph2's lgkm0 (everything is
// cached in VGPRs), so overwriting buf b with t+2 at ph3/ph4 is ordered by
// ph2's trailing barrier. Raw s_barrier throughout (no vmcnt(0) drain).
// ---------------------------------------------------------------------------
__global__ __launch_bounds__(512, 2) void gemm_qkv_8ph_kernel(
    const __bf16* __restrict__ A,
    const __bf16* __restrict__ B0, const __bf16* __restrict__ B1, const __bf16* __restrict__ B2,
    __bf16* __restrict__ C0, __bf16* __restrict__ C1, __bf16* __restrict__ C2)
{
    constexpr int BM = 256, BK = 64, KD = D_MODEL, NT = KD / BK;   // 32 K-tiles

    __shared__ __align__(16) __bf16 As[2][BM * BK];   // 2 x 32 KB
    __shared__ __align__(16) __bf16 Bs[2][BM * BK];   // 2 x 32 KB

    // XCD-aware swizzle over the 192-block grid (192 % 8 == 0 -> bijective)
    const int flat = (int)blockIdx.x + 8 * ((int)blockIdx.y + 8 * (int)blockIdx.z);
    const int swz  = (flat & 7) * 24 + (flat >> 3);
    const int bz   = swz >> 6;
    const int bm   = (swz & 7) * BM;
    const int bn   = ((swz >> 3) & 7) * BM;

    const __bf16* Bmat = bz == 0 ? B0 : (bz == 1 ? B1 : B2);
    __bf16* Cmat       = bz == 0 ? C0 : (bz == 1 ? C1 : C2);

    const int tid  = threadIdx.x;
    const int lane = tid & 63;
    const int wave = tid >> 6;      // 0..7
    const int r15  = lane & 15;
    const int quad = lane >> 4;
    const int r7   = r15 & 7;
    const int wm   = wave >> 2;     // 0..1  : 128-row M half
    const int wn   = wave & 3;      // 0..3  : 64-col  N slice

    // Staging: per half-tile (128 rows x 64 cols) each thread issues 2
    // global_load_lds. Wave w, load j covers LDS rows (w*2+j)*8 .. +7.
    // Lane l -> row (l>>3), 16B chunk position (l&7); source chunk is
    // pre-XORed with row&7 so the linear LDS write realizes the swizzle.
    const int sr8 = lane >> 3;
    const int sck = (lane & 7) ^ sr8;
    const __bf16* Ap = A    + (size_t)(bm + wave * 16 + sr8) * KD + sck * 8;
    const __bf16* Bp = Bmat + (size_t)(bn + wave * 16 + sr8) * KD + sck * 8;

    auto stageA = [&](int buf, int h, int kt) {
        const __bf16* s = Ap + (size_t)(h * 128) * KD + kt;
        __bf16* d = &As[buf][h * 8192 + wave * 1024];
        async_copy16(s, d);
        async_copy16(s + 8 * KD, d + 512);
    };
    auto stageB = [&](int buf, int h, int kt) {
        const __bf16* s = Bp + (size_t)(h * 128) * KD + kt;
        __bf16* d = &Bs[buf][h * 8192 + wave * 1024];
        async_copy16(s, d);
        async_copy16(s + 8 * KD, d + 512);
    };

    f32x4 acc[8][4] = {};   // [M frag 0..7][N frag 0..3], M1 = +4, N1 = +2

    // prologue: tile 0 -> buf0, tile 1 -> buf1 (8 loads/thread each)
    stageA(0, 0, 0);  stageA(0, 1, 0);  stageB(0, 0, 0);  stageB(0, 1, 0);
    stageA(1, 0, BK); stageA(1, 1, BK); stageB(1, 0, BK); stageB(1, 1, BK);
    asm volatile("s_waitcnt vmcnt(8)" ::: "memory");   // tile 0 landed, tile 1 in flight
    __builtin_amdgcn_s_barrier();

    for (int t = 0; t < NT; t++) {
        const int b = t & 1;
        const __bf16* Asb = As[b];
        const __bf16* Bsb = Bs[b];
        const bool pf = (t + 2 < NT);
        const int ktp = (t + 2) * BK;

        bf16x8 a0[4][2], a1[4][2], b0[2][2], b1[2][2];

        // ---- phase 1: read A(M0), B(N0); MFMA M0N0 ----
        #pragma unroll
        for (int mf = 0; mf < 4; mf++)
            #pragma unroll
            for (int s = 0; s < 2; s++)
                a0[mf][s] = ld_frag(Asb, wm * 128 + mf * 16 + r15, s, quad, r7);
        #pragma unroll
        for (int nf = 0; nf < 2; nf++)
            #pragma unroll
            for (int s = 0; s < 2; s++)
                b0[nf][s] = ld_frag(Bsb, wn * 64 + nf * 16 + r15, s, quad, r7);
        __builtin_amdgcn_s_barrier();
        asm volatile("s_waitcnt lgkmcnt(0)" ::: "memory");
        __builtin_amdgcn_sched_barrier(0);
        __builtin_amdgcn_s_setprio(1);
        #pragma unroll
        for (int mf = 0; mf < 4; mf++)
            #pragma unroll
            for (int nf = 0; nf < 2; nf++)
                #pragma unroll
                for (int s = 0; s < 2; s++)
                    acc[mf][nf] = __builtin_amdgcn_mfma_f32_16x16x32_bf16(a0[mf][s], b0[nf][s], acc[mf][nf], 0, 0, 0);
        __builtin_amdgcn_s_setprio(0);
        __builtin_amdgcn_sched_barrier(0);
        __builtin_amdgcn_s_barrier();

        // ---- phase 2: read A(M1), B(N1); MFMA M1N1 ----
        #pragma unroll
        for (int mf = 0; mf < 4; mf++)
            #pragma unroll
            for (int s = 0; s < 2; s++)
                a1[mf][s] = ld_frag(Asb, wm * 128 + 64 + mf * 16 + r15, s, quad, r7);
        #pragma unroll
        for (int nf = 0; nf < 2; nf++)
            #pragma unroll
            for (int s = 0; s < 2; s++)
                b1[nf][s] = ld_frag(Bsb, wn * 64 + 32 + nf * 16 + r15, s, quad, r7);
        __builtin_amdgcn_s_barrier();
        asm volatile("s_waitcnt lgkmcnt(0)" ::: "memory");
        __builtin_amdgcn_sched_barrier(0);
        __builtin_amdgcn_s_setprio(1);
        #pragma unroll
        for (int mf = 0; mf < 4; mf++)
            #pragma unroll
            for (int nf = 0; nf < 2; nf++)
                #pragma unroll
                for (int s = 0; s < 2; s++)
                    acc[4 + mf][2 + nf] = __builtin_amdgcn_mfma_f32_16x16x32_bf16(a1[mf][s], b1[nf][s], acc[4 + mf][2 + nf], 0, 0, 0);
        __builtin_amdgcn_s_setprio(0);
        __builtin_amdgcn_sched_barrier(0);
        __builtin_amdgcn_s_barrier();

        // ---- phase 3: stage half0 of tile t+2 into buf b; MFMA M0N1 ----
        if (pf) { stageA(b, 0, ktp); stageB(b, 0, ktp); }
        __builtin_amdgcn_s_barrier();
        __builtin_amdgcn_s_setprio(1);
        #pragma unroll
        for (int mf = 0; mf < 4; mf++)
            #pragma unroll
            for (int nf = 0; nf < 2; nf++)
                #pragma unroll
                for (int s = 0; s < 2; s++)
                    acc[mf][2 + nf] = __builtin_amdgcn_mfma_f32_16x16x32_bf16(a0[mf][s], b1[nf][s], acc[mf][2 + nf], 0, 0, 0);
        __builtin_amdgcn_s_setprio(0);
        __builtin_amdgcn_sched_barrier(0);
        __builtin_amdgcn_s_barrier();

        // ---- phase 4: stage half1 of t+2; MFMA M1N0; counted vmcnt ----
        if (pf) { stageA(b, 1, ktp); stageB(b, 1, ktp); }
        __builtin_amdgcn_s_barrier();
        __builtin_amdgcn_s_setprio(1);
        #pragma unroll
        for (int mf = 0; mf < 4; mf++)
            #pragma unroll
            for (int nf = 0; nf < 2; nf++)
                #pragma unroll
                for (int s = 0; s < 2; s++)
                    acc[4 + mf][nf] = __builtin_amdgcn_mfma_f32_16x16x32_bf16(a1[mf][s], b0[nf][s], acc[4 + mf][nf], 0, 0, 0);
        __builtin_amdgcn_s_setprio(0);
        __builtin_amdgcn_sched_barrier(0);
        if (t + 1 < NT) {
            if (pf) asm volatile("s_waitcnt vmcnt(8)" ::: "memory");   // t+1 landed, t+2 in flight
            else    asm volatile("s_waitcnt vmcnt(0)" ::: "memory");   // tail: nothing newer
        }
        __builtin_amdgcn_s_barrier();
    }

    // ---- epilogue ----
    #pragma unroll
    for (int mf = 0; mf < 8; mf++) {
        #pragma unroll
        for (int r = 0; r < 4; r++) {
            const size_t row = (size_t)(bm + wm * 128 + mf * 16 + quad * 4 + r);
            #pragma unroll
            for (int nf = 0; nf < 4; nf++) {
                const size_t col = (size_t)(bn + wn * 64 + nf * 16 + r15);
                Cmat[row * D_MODEL + col] = (__bf16)acc[mf][nf][r];
            }
        }
    }
}

// ---------------------------------------------------------------------------
// Split-K GEMM for the final projection (fp32 atomic epilogue), BK=32 dbuf.
// ---------------------------------------------------------------------------
__global__ __launch_bounds__(256) void gemm_bt_splitk_kernel(
    const __bf16* __restrict__ A, const __bf16* __restrict__ Bm, float* __restrict__ C)
{
    constexpr int BM = 128, BK = 32, KD = D_MODEL, NIT = (KD / 2) / BK;
    __shared__ __align__(16) __bf16 As[2][BM * BK];
    __shared__ __align__(16) __bf16 Bs[2][BM * BK];

    const int lane = threadIdx.x & 63;
    const int wave = threadIdx.x >> 6;
    const int r15  = lane & 15;
    const int quad = lane >> 4;
    const int bm = blockIdx.x * BM;
    const int bn = blockIdx.y * BM;
    const int wm = (wave >> 1) * 64;
    const int wn = (wave & 1) * 64;
    const int kbase = blockIdx.z * (KD / 2);

    f32x4 acc[4][4] = {};
    const int srow = wave * 32 + (lane >> 2);
    const int sg   = (lane & 3) ^ ((lane >> 2) & 3);

    const __bf16* Arow0 = A  + (size_t)(bm + srow)      * KD + kbase + sg * 8;
    const __bf16* Arow1 = A  + (size_t)(bm + srow + 16) * KD + kbase + sg * 8;
    const __bf16* Brow0 = Bm + (size_t)(bn + srow)      * KD + kbase + sg * 8;
    const __bf16* Brow1 = Bm + (size_t)(bn + srow + 16) * KD + kbase + sg * 8;

    async_copy16(Arow0, &As[0][wave * 1024]);
    async_copy16(Arow1, &As[0][wave * 1024 + 512]);
    async_copy16(Brow0, &Bs[0][wave * 1024]);
    async_copy16(Brow1, &Bs[0][wave * 1024 + 512]);

    for (int it = 0; it < NIT; it++) {
        const int buf = it & 1;
        __syncthreads();

        if (it + 1 < NIT) {
            const int k0 = (it + 1) * BK;
            const int nb = buf ^ 1;
            async_copy16(Arow0 + k0, &As[nb][wave * 1024]);
            async_copy16(Arow1 + k0, &As[nb][wave * 1024 + 512]);
            async_copy16(Brow0 + k0, &Bs[nb][wave * 1024]);
            async_copy16(Brow1 + k0, &Bs[nb][wave * 1024 + 512]);
        }

        bf16x8 av[4], bv[4];
        #pragma unroll
        for (int mt = 0; mt < 4; mt++)
            av[mt] = *(const bf16x8*)&As[buf][(wm + mt * 16 + r15) * BK + ((quad ^ (r15 & 3)) << 3)];
        #pragma unroll
        for (int nt = 0; nt < 4; nt++)
            bv[nt] = *(const bf16x8*)&Bs[buf][(wn + nt * 16 + r15) * BK + ((quad ^ (r15 & 3)) << 3)];
        #pragma unroll
        for (int mt = 0; mt < 4; mt++)
            #pragma unroll
            for (int nt = 0; nt < 4; nt++)
                acc[mt][nt] = __builtin_amdgcn_mfma_f32_16x16x32_bf16(av[mt], bv[nt], acc[mt][nt], 0, 0, 0);
    }

    #pragma unroll
    for (int mt = 0; mt < 4; mt++) {
        #pragma unroll
        for (int r = 0; r < 4; r++) {
            size_t row = bm + wm + mt * 16 + quad * 4 + r;
            #pragma unroll
            for (int nt = 0; nt < 4; nt++) {
                size_t col = bn + wn + nt * 16 + r15;
                atomicAdd(&C[row * D_MODEL + col], acc[mt][nt][r]);
            }
        }
    }
}

// ---------------------------------------------------------------------------
// Preproc q/k: conv(K=4)+SiLU+RMSNorm+RoPE, pure-register.
// q pre-scaled by 1/sqrt(HD); outer rotary negation dropped (cancels in qk^T).
// ---------------------------------------------------------------------------
__global__ __launch_bounds__(256) void preproc_qk_kernel(
    const __bf16* __restrict__ q_raw, const __bf16* __restrict__ k_raw,
    const float* __restrict__ cwq, const float* __restrict__ cwk,
    const float* __restrict__ qnw, const float* __restrict__ knw,
    const float* __restrict__ cosb, const float* __restrict__ sinb,
    __bf16* __restrict__ q_proc, __bf16* __restrict__ k_proc)
{
    const int t = blockIdx.x;
    const int which = blockIdx.y;
    const __bf16* X = which ? k_raw : q_raw;
    const float*  W = which ? cwk : cwq;
    const float*  nw = which ? knw : qnw;
    __bf16* P = which ? k_proc : q_proc;
    const float SC = which ? 1.0f : 0.08838834764831845f;  // 1/sqrt(128) folded into q

    const int tid = threadIdx.x;
    const int c0  = tid * 8;
    const int h   = tid >> 4;
    const int dl0 = (tid & 15) * 8;

    f32x4 wv[8];
    #pragma unroll
    for (int i = 0; i < 8; i++) wv[i] = *(const f32x4*)&W[(c0 + i) * 4];

    float acc[8] = {};
    #pragma unroll
    for (int j = 0; j < 4; j++) {
        int tt = t + j - 3;
        if (tt >= 0) {
            bf16x8 xv = *(const bf16x8*)&X[(size_t)tt * D_MODEL + c0];
            #pragma unroll
            for (int i = 0; i < 8; i++) acc[i] += (float)xv[i] * wv[i][j];
        }
    }
    float sil[8], ss = 0.f;
    #pragma unroll
    for (int i = 0; i < 8; i++) {
        float s = acc[i] / (1.f + __expf(-acc[i]));
        sil[i] = s; ss += s * s;
    }
    #pragma unroll
    for (int off = 1; off < 16; off <<= 1) ss += __shfl_xor(ss, off);
    float inv = rsqrtf(ss * (1.f / 128.f) + 1e-5f);

    f32x4 nv0 = *(const f32x4*)&nw[dl0];
    f32x4 nv1 = *(const f32x4*)&nw[dl0 + 4];
    float yn[8];
    #pragma unroll
    for (int i = 0; i < 8; i++) yn[i] = sil[i] * inv * (i < 4 ? nv0[i] : nv1[i - 4]);

    float partner[8];
    #pragma unroll
    for (int i = 0; i < 8; i++) partner[i] = __shfl_xor(yn[i], 4);  // dl ^ 32

    bf16x8 o;
    if (dl0 < RD_ROT) {
        f32x4 cv0 = *(const f32x4*)&cosb[t * RD_ROT + dl0];
        f32x4 cv1 = *(const f32x4*)&cosb[t * RD_ROT + dl0 + 4];
        f32x4 sv0 = *(const f32x4*)&sinb[t * RD_ROT + dl0];
        f32x4 sv1 = *(const f32x4*)&sinb[t * RD_ROT + dl0 + 4];
        #pragma unroll
        for (int i = 0; i < 8; i++) {
            int dl = dl0 + i;
            float c = i < 4 ? cv0[i] : cv1[i - 4];
            float s = i < 4 ? sv0[i] : sv1[i - 4];
            float rot = (dl < 32) ? -partner[i] : partner[i];  // rotate_half
            o[i] = (__bf16)((yn[i] * c + rot * s) * SC);
        }
    } else {
        #pragma unroll
        for (int i = 0; i < 8; i++) o[i] = (__bf16)(yn[i] * SC);
    }
    *(bf16x8*)&P[((size_t)h * T_SEQ + t) * HDIM + dl0] = o;
}

// ---------------------------------------------------------------------------
// Preproc v: conv+SiLU, transposed (H, HD, T) store, bf16x8 per thread.
// ---------------------------------------------------------------------------
__global__ __launch_bounds__(128) void preproc_v_kernel(
    const __bf16* __restrict__ v_raw, const float* __restrict__ cwv,
    __bf16* __restrict__ v_t)
{
    const int t0 = blockIdx.x * 8;
    const int h = blockIdx.y;
    const int dl = threadIdx.x;
    const int d = h * HDIM + dl;

    f32x4 wv = *(const f32x4*)&cwv[d * 4];
    float x[11];
    #pragma unroll
    for (int m = 0; m < 11; m++) {
        int tt = t0 - 3 + m;
        x[m] = (tt >= 0) ? (float)v_raw[(size_t)tt * D_MODEL + d] : 0.f;
    }
    bf16x8 o;
    #pragma unroll
    for (int r = 0; r < 8; r++) {
        float y = x[r] * wv[0] + x[r + 1] * wv[1] + x[r + 2] * wv[2] + x[r + 3] * wv[3];
        o[r] = (__bf16)(y / (1.f + __expf(-y)));
    }
    *(bf16x8*)&v_t[((size_t)h * HDIM + dl) * T_SEQ + t0] = o;
}

// ---------------------------------------------------------------------------
// Flash attention, causal — 4 waves x 16 q-rows, double-buffered K/V staging,
// STATIC-MAX softmax (q,k RMS-normed + RoPE norm-preserving + folded 1/sqrt(128)
// => |s| <= 11.4, exp safe). Zero cross-lane ops in the k-loop.
// ---------------------------------------------------------------------------
__global__ __launch_bounds__(256, 2) void attn_kernel(
    const __bf16* __restrict__ Qp,   // (H, T, HD), pre-scaled
    const __bf16* __restrict__ Kp,   // (H, T, HD)
    const __bf16* __restrict__ Vt,   // (H, HD, T)
    __bf16* __restrict__ Op)         // (T, D)
{
    constexpr int TK = 64, PSTR = 72;
    __shared__ __align__(16) __bf16 Ks[2][TK * HDIM];   // 2 x 16 KB
    __shared__ __align__(16) __bf16 Vs[2][HDIM * TK];   // 2 x 16 KB
    __shared__ __align__(16) __bf16 Ps[64 * PSTR];      // 9 KB

    const int lane = threadIdx.x & 63;
    const int wave = threadIdx.x >> 6;
    const int r15  = lane & 15;
    const int quad = lane >> 4;
    const int h = blockIdx.y;
    const int qi = (blockIdx.y & 8) ? ((int)gridDim.x - 1 - (int)blockIdx.x) : (int)blockIdx.x;
    const int q0 = qi * TK;

    const __bf16* Kb = Kp + (size_t)h * T_SEQ * HDIM;
    const __bf16* Vb = Vt + (size_t)h * HDIM * T_SEQ;

    const int kchunk = wave * 4;
    const int krow_l = (lane >> 4);
    const int kg     = lane & 15;
    const int vrow_l = (lane >> 3);
    const int vg     = lane & 7;

    bf16x8 qf[4];
    const __bf16* qbase = Qp + ((size_t)h * T_SEQ + q0 + wave * 16 + r15) * HDIM;
    #pragma unroll
    for (int s = 0; s < 4; s++) qf[s] = *(const bf16x8*)(qbase + s * 32 + quad * 8);

    f32x4 oacc[8] = {};
    float lsum[4] = {};

    const int ntk = qi + 1;

    #pragma unroll
    for (int i = 0; i < 4; i++) {
        int ck = kchunk + i;
        int krow = ck * 4 + krow_l;
        int vrow = ck * 8 + vrow_l;
        async_copy16(Kb + (size_t)krow * HDIM + (kg ^ (krow & 15)) * 8, &Ks[0][ck * 512]);
        async_copy16(Vb + (size_t)vrow * T_SEQ + (vg ^ (vrow & 7)) * 8, &Vs[0][ck * 512]);
    }

    for (int it = 0; it < ntk; it++) {
        const int buf = it & 1;
        const bool last = (it == ntk - 1);
        __syncthreads();

        if (!last) {
            const int tkn = (it + 1) * TK;
            const int nbuf = buf ^ 1;
            #pragma unroll
            for (int i = 0; i < 4; i++) {
                int ck = kchunk + i;
                int krow = ck * 4 + krow_l;
                int vrow = ck * 8 + vrow_l;
                async_copy16(Kb + (size_t)(tkn + krow) * HDIM + (kg ^ (krow & 15)) * 8, &Ks[nbuf][ck * 512]);
                async_copy16(Vb + (size_t)vrow * T_SEQ + tkn + (vg ^ (vrow & 7)) * 8, &Vs[nbuf][ck * 512]);
            }
        }

        // ---- S = Q K^T ----
        f32x4 sacc[4] = {};
        #pragma unroll
        for (int s = 0; s < 4; s++) {
            #pragma unroll
            for (int nt = 0; nt < 4; nt++) {
                bf16x8 kf = *(const bf16x8*)&Ks[buf][(nt * 16 + r15) * HDIM + (((s * 4 + quad) ^ r15) << 3)];
                sacc[nt] = __builtin_amdgcn_mfma_f32_16x16x32_bf16(qf[s], kf, sacc[nt], 0, 0, 0);
            }
        }

        // ---- p = exp(s), static max; mask only on the diagonal tile ----
        #pragma unroll
        for (int nt = 0; nt < 4; nt++) {
            #pragma unroll
            for (int r = 0; r < 4; r++) {
                float p = __expf(sacc[nt][r]);
                if (last) {
                    int qrow = q0 + wave * 16 + quad * 4 + r;
                    int kcol = it * TK + nt * 16 + r15;
                    if (kcol > qrow) p = 0.f;
                }
                sacc[nt][r] = p;
                lsum[r] += p;
            }
        }

        // ---- P: C-layout -> LDS (wave-private rows, no barrier) ----
        #pragma unroll
        for (int nt = 0; nt < 4; nt++)
            #pragma unroll
            for (int r = 0; r < 4; r++)
                Ps[(wave * 16 + quad * 4 + r) * PSTR + nt * 16 + r15] = (__bf16)sacc[nt][r];

        // ---- O += P V ----
        #pragma unroll
        for (int s2 = 0; s2 < 2; s2++) {
            bf16x8 pf = *(const bf16x8*)&Ps[(wave * 16 + r15) * PSTR + s2 * 32 + quad * 8];
            #pragma unroll
            for (int nt = 0; nt < 8; nt++) {
                bf16x8 vf = *(const bf16x8*)&Vs[buf][(nt * 16 + r15) * TK + (((s2 * 4 + quad) ^ (r15 & 7)) << 3)];
                oacc[nt] = __builtin_amdgcn_mfma_f32_16x16x32_bf16(pf, vf, oacc[nt], 0, 0, 0);
            }
        }
    }

    #pragma unroll
    for (int r = 0; r < 4; r++) {
        float l = lsum[r];
        #pragma unroll
        for (int off = 1; off < 16; off <<= 1) l += __shfl_xor(l, off);
        float inv = 1.0f / l;
        size_t row = q0 + wave * 16 + quad * 4 + r;
        #pragma unroll
        for (int nt = 0; nt < 8; nt++)
            Op[row * D_MODEL + h * HDIM + nt * 16 + r15] = (__bf16)(oacc[nt][r] * inv);
    }
}

// ---------------------------------------------------------------------------
extern "C" void kernel_launch(void* const* d_in, const int* in_sizes, int n_in,
                              void* d_out, int out_size, void* d_ws, size_t ws_size,
                              hipStream_t stream) {
    (void)in_sizes; (void)n_in; (void)out_size; (void)ws_size;
    const float* hidden = (const float*)d_in[0];
    const float* cosb   = (const float*)d_in[1];
    const float* sinb   = (const float*)d_in[2];
    const float* Wq     = (const float*)d_in[3];
    const float* Wk     = (const float*)d_in[4];
    const float* Wv     = (const float*)d_in[5];
    const float* Wo     = (const float*)d_in[6];
    const float* cwq    = (const float*)d_in[7];
    const float* cwk    = (const float*)d_in[8];
    const float* cwv    = (const float*)d_in[9];
    const float* qnw    = (const float*)d_in[10];
    const float* knw    = (const float*)d_in[11];

    const size_t NEL = (size_t)T_SEQ * D_MODEL;
    __bf16* ws = (__bf16*)d_ws;
    __bf16* h_bf   = ws + 0 * NEL;   // later reused as attn_b
    __bf16* Wq_bf  = ws + 1 * NEL;   // later reused as q_proc
    __bf16* Wk_bf  = ws + 2 * NEL;   // later reused as k_proc
    __bf16* Wv_bf  = ws + 3 * NEL;   // later reused as v_t
    __bf16* Wo_bf  = ws + 4 * NEL;   // persists to final GEMM
    __bf16* q_raw  = ws + 5 * NEL;
    __bf16* k_raw  = ws + 6 * NEL;
    __bf16* v_raw  = ws + 7 * NEL;
    __bf16* q_proc = Wq_bf;
    __bf16* k_proc = Wk_bf;
    __bf16* v_t    = Wv_bf;
    __bf16* attn_b = h_bf;
    float*  out    = (float*)d_out;

    // 0. cast fp32 inputs to bf16
    cast_kernel<<<dim3(T_SEQ, 5), 256, 0, stream>>>(hidden, Wq, Wk, Wv, Wo,
                                                    h_bf, Wq_bf, Wk_bf, Wv_bf, Wo_bf);
    // 1. q,k,v = hidden @ {Wq,Wk,Wv}^T — 256x256 tile, 4-phase counted-vmcnt
    gemm_qkv_8ph_kernel<<<dim3(8, 8, 3), 512, 0, stream>>>(
        h_bf, Wq_bf, Wk_bf, Wv_bf, q_raw, k_raw, v_raw);
    // 2. preproc
    preproc_qk_kernel<<<dim3(T_SEQ, 2), 256, 0, stream>>>(
        q_raw, k_raw, cwq, cwk, qnw, knw, cosb, sinb, q_proc, k_proc);
    preproc_v_kernel<<<dim3(T_SEQ / 8, NH), 128, 0, stream>>>(v_raw, cwv, v_t);
    // 3. causal flash attention (dbuf staging + static-max softmax)
    attn_kernel<<<dim3(T_SEQ / 64, NH), 256, 0, stream>>>(q_proc, k_proc, v_t, attn_b);
    // 4. out = attn @ Wo^T, split-K x2 with fp32 atomic epilogue (dbuf)
    hipMemsetAsync(d_out, 0, NEL * sizeof(float), stream);
    gemm_bt_splitk_kernel<<<dim3(16, 16, 2), 256, 0, stream>>>(attn_b, Wo_bf, out);
}

// Round 2
// 333.223 us; speedup vs baseline: 1.0303x; 1.0227x over previous
//
#include <hip/hip_runtime.h>
#include <hip/hip_bf16.h>

// Problem constants (B=1)
#define T_SEQ 2048
#define D_MODEL 2048
#define NH 16
#define HDIM 128
#define RD_ROT 64

typedef __bf16 bf16x8 __attribute__((ext_vector_type(8)));
typedef float f32x4 __attribute__((ext_vector_type(4)));

__device__ __forceinline__ void async_copy16(const __bf16* g, __bf16* l) {
    __builtin_amdgcn_global_load_lds(
        (const __attribute__((address_space(1))) void*)g,
        (__attribute__((address_space(3))) void*)l, 16, 0, 0);
}

// ---------------------------------------------------------------------------
// Cast fp32 -> bf16 for the 5 GEMM operands (hidden, Wq, Wk, Wv, Wo).
// ---------------------------------------------------------------------------
__global__ __launch_bounds__(256) void cast_kernel(
    const float* __restrict__ s0, const float* __restrict__ s1, const float* __restrict__ s2,
    const float* __restrict__ s3, const float* __restrict__ s4,
    __bf16* __restrict__ d0, __bf16* __restrict__ d1, __bf16* __restrict__ d2,
    __bf16* __restrict__ d3, __bf16* __restrict__ d4)
{
    const float* s; __bf16* d;
    switch (blockIdx.y) {
        case 0: s = s0; d = d0; break;
        case 1: s = s1; d = d1; break;
        case 2: s = s2; d = d2; break;
        case 3: s = s3; d = d3; break;
        default: s = s4; d = d4; break;
    }
    size_t base = (size_t)blockIdx.x * D_MODEL + (size_t)threadIdx.x * 8;
    f32x4 a = *(const f32x4*)(s + base);
    f32x4 b = *(const f32x4*)(s + base + 4);
    bf16x8 o;
    #pragma unroll
    for (int i = 0; i < 4; i++) { o[i] = (__bf16)a[i]; o[i + 4] = (__bf16)b[i]; }
    *(bf16x8*)(d + base) = o;
}

// ---------------------------------------------------------------------------
// LDS fragment read: rows are 64 bf16 = 128 B = exactly 32 banks; st_16x32
// XOR swizzle (chunk ^= row&7), realized on the write side by pre-swizzling
// the GLOBAL source of global_load_lds (dest stays linear).
// ---------------------------------------------------------------------------
__device__ __forceinline__ bf16x8 ld_frag(const __bf16* lds, int rr, int s, int quad, int r7) {
    return *(const bf16x8*)&lds[rr * 64 + ((((s << 2) + quad) ^ r7) << 3)];
}

// ---------------------------------------------------------------------------
// QKV GEMM: C = A @ B^T, 256x256 tile, BK=64, 512 threads (8 waves, 2M x 4N).
// SOFTWARE-PIPELINED 4-phase schedule: ds_reads issued in phase p feed phase
// p+1's MFMA (counted lgkm waits auto-inserted by the compiler), ONE barrier
// per phase, ONE counted vmcnt per K-tile. Quadrant order M0N0,M0N1,M1N1,M1N0
// gives per-phase read deltas 4,8,0,12 (the m201 "4 or 8" pattern).
//
// Per tile t (buf b = t&1, other buf = b^1 holds tile t+1):
//   ph1: read b1(t) [4]          | MFMA q1 (a0,b0)           | bar
//   ph2: read a1(t) [8]          | MFMA q2 (a0,b1)           | bar
//   ph3: stage B(t+2)->buf b [4] | MFMA q3 (a1,b1) | vmcnt(4)| bar
//   ph4: read a0(t+1) [8] from buf b^1; stage A(t+2)->buf b [4]
//        | MFMA q4 (a1,b0) | read b0(t+1) [4] from buf b^1   | bar
// Region safety (1 barrier/phase): B of buf b last consumed at ph2's
// pre-MFMA wait -> B-stage at ph3 ordered by ph2 barrier; A consumed at ph3
// -> A-stage at ph4. t+1 frags staged at t-1 ph3/ph4 are drained by ph3's
// vmcnt(4) (leaves only this tile's 4 B-stages) + ph3 barrier -> read at ph4.
// Tail tiles with no own stages use vmcnt(0) (counted wait would under-drain).
// ---------------------------------------------------------------------------
__global__ __launch_bounds__(512, 2) void gemm_qkv_pipe_kernel(
    const __bf16* __restrict__ A,
    const __bf16* __restrict__ B0, const __bf16* __restrict__ B1, const __bf16* __restrict__ B2,
    __bf16* __restrict__ C0, __bf16* __restrict__ C1, __bf16* __restrict__ C2)
{
    constexpr int BM = 256, BK = 64, KD = D_MODEL, NT = KD / BK;   // 32 K-tiles

    __shared__ __align__(16) __bf16 As[2][BM * BK];   // 2 x 32 KB
    __shared__ __align__(16) __bf16 Bs[2][BM * BK];   // 2 x 32 KB

    // XCD-aware swizzle over the 192-block grid (192 % 8 == 0 -> bijective)
    const int flat = (int)blockIdx.x + 8 * ((int)blockIdx.y + 8 * (int)blockIdx.z);
    const int swz  = (flat & 7) * 24 + (flat >> 3);
    const int bz   = swz >> 6;
    const int bm   = (swz & 7) * BM;
    const int bn   = ((swz >> 3) & 7) * BM;

    const __bf16* Bmat = bz == 0 ? B0 : (bz == 1 ? B1 : B2);
    __bf16* Cmat       = bz == 0 ? C0 : (bz == 1 ? C1 : C2);

    const int tid  = threadIdx.x;
    const int lane = tid & 63;
    const int wave = tid >> 6;      // 0..7
    const int r15  = lane & 15;
    const int quad = lane >> 4;
    const int r7   = r15 & 7;
    const int wm   = wave >> 2;     // 0..1  : 128-row M half
    const int wn   = wave & 3;      // 0..3  : 64-col  N slice

    // Staging: lane l -> row (l>>3), chunk (l&7); source chunk pre-XORed with
    // row&7 so the linear LDS write realizes the swizzle.
    const int sr8 = lane >> 3;
    const int sck = (lane & 7) ^ sr8;
    const __bf16* Ap = A    + (size_t)(bm + wave * 16 + sr8) * KD + sck * 8;
    const __bf16* Bp = Bmat + (size_t)(bn + wave * 16 + sr8) * KD + sck * 8;

    auto stageA = [&](int buf, int h, int kt) {
        const __bf16* s = Ap + (size_t)(h * 128) * KD + kt;
        __bf16* d = &As[buf][h * 8192 + wave * 1024];
        async_copy16(s, d);
        async_copy16(s + 8 * KD, d + 512);
    };
    auto stageB = [&](int buf, int h, int kt) {
        const __bf16* s = Bp + (size_t)(h * 128) * KD + kt;
        __bf16* d = &Bs[buf][h * 8192 + wave * 1024];
        async_copy16(s, d);
        async_copy16(s + 8 * KD, d + 512);
    };

    f32x4 acc[8][4] = {};   // [M frag 0..7][N frag 0..3]; M1 = +4, N1 = +2
    bf16x8 a0[4][2], a1[4][2], b0[2][2], b1[2][2];

    auto mfma16 = [&](int mb, int nb, bf16x8 (&av)[4][2], bf16x8 (&bv)[2][2]) {
        #pragma unroll
        for (int mf = 0; mf < 4; mf++)
            #pragma unroll
            for (int nf = 0; nf < 2; nf++)
                #pragma unroll
                for (int s = 0; s < 2; s++)
                    acc[mb + mf][nb + nf] =
                        __builtin_amdgcn_mfma_f32_16x16x32_bf16(av[mf][s], bv[nf][s], acc[mb + mf][nb + nf], 0, 0, 0);
    };

    // ---- prologue: stage t0 -> buf0, t1 -> buf1 (slot order B then A) ----
    stageB(0, 0, 0);  stageB(0, 1, 0);  stageA(0, 0, 0);  stageA(0, 1, 0);
    stageB(1, 0, BK); stageB(1, 1, BK); stageA(1, 0, BK); stageA(1, 1, BK);
    asm volatile("s_waitcnt vmcnt(8)" ::: "memory");   // t0 landed, t1 in flight
    __builtin_amdgcn_s_barrier();
    __builtin_amdgcn_sched_barrier(0);
    // q1(t0) operands
    #pragma unroll
    for (int mf = 0; mf < 4; mf++)
        #pragma unroll
        for (int s = 0; s < 2; s++)
            a0[mf][s] = ld_frag(As[0], wm * 128 + mf * 16 + r15, s, quad, r7);
    #pragma unroll
    for (int nf = 0; nf < 2; nf++)
        #pragma unroll
        for (int s = 0; s < 2; s++)
            b0[nf][s] = ld_frag(Bs[0], wn * 64 + nf * 16 + r15, s, quad, r7);

    for (int t = 0; t < NT; t++) {
        const int b = t & 1;
        const __bf16* Asb = As[b];
        const __bf16* Bsb = Bs[b];
        const __bf16* Aso = As[b ^ 1];
        const __bf16* Bso = Bs[b ^ 1];
        const bool pf = (t + 2 < NT);
        const int ktp = (t + 2) * BK;

        // ---- ph1: read b1(t) [feeds ph2]; MFMA q1 (a0,b0) ----
        #pragma unroll
        for (int nf = 0; nf < 2; nf++)
            #pragma unroll
            for (int s = 0; s < 2; s++)
                b1[nf][s] = ld_frag(Bsb, wn * 64 + 32 + nf * 16 + r15, s, quad, r7);
        __builtin_amdgcn_sched_barrier(0);
        __builtin_amdgcn_s_setprio(1);
        mfma16(0, 0, a0, b0);
        __builtin_amdgcn_s_setprio(0);
        __builtin_amdgcn_sched_barrier(0);
        __builtin_amdgcn_s_barrier();
        __builtin_amdgcn_sched_barrier(0);

        // ---- ph2: read a1(t) [feeds ph3]; MFMA q2 (a0,b1) ----
        #pragma unroll
        for (int mf = 0; mf < 4; mf++)
            #pragma unroll
            for (int s = 0; s < 2; s++)
                a1[mf][s] = ld_frag(Asb, wm * 128 + 64 + mf * 16 + r15, s, quad, r7);
        __builtin_amdgcn_sched_barrier(0);
        __builtin_amdgcn_s_setprio(1);
        mfma16(0, 2, a0, b1);
        __builtin_amdgcn_s_setprio(0);
        __builtin_amdgcn_sched_barrier(0);
        __builtin_amdgcn_s_barrier();
        __builtin_amdgcn_sched_barrier(0);

        // ---- ph3: stage B(t+2); MFMA q3 (a1,b1); counted vmcnt ----
        if (pf) { stageB(b, 0, ktp); stageB(b, 1, ktp); }
        __builtin_amdgcn_sched_barrier(0);
        __builtin_amdgcn_s_setprio(1);
        mfma16(4, 2, a1, b1);
        __builtin_amdgcn_s_setprio(0);
        __builtin_amdgcn_sched_barrier(0);
        if (pf) asm volatile("s_waitcnt vmcnt(4)" ::: "memory");   // drain t-1's stages (t+1's data)
        else    asm volatile("s_waitcnt vmcnt(0)" ::: "memory");   // tail: counted wait would under-drain
        __builtin_amdgcn_s_barrier();
        __builtin_amdgcn_sched_barrier(0);

        // ---- ph4: read a0(t+1); stage A(t+2); MFMA q4 (a1,b0); read b0(t+1) ----
        #pragma unroll
        for (int mf = 0; mf < 4; mf++)
            #pragma unroll
            for (int s = 0; s < 2; s++)
                a0[mf][s] = ld_frag(Aso, wm * 128 + mf * 16 + r15, s, quad, r7);
        if (pf) { stageA(b, 0, ktp); stageA(b, 1, ktp); }
        __builtin_amdgcn_sched_barrier(0);
        __builtin_amdgcn_s_setprio(1);
        mfma16(4, 0, a1, b0);   // consumes old b0 before it is overwritten below
        __builtin_amdgcn_s_setprio(0);
        __builtin_amdgcn_sched_barrier(0);
        #pragma unroll
        for (int nf = 0; nf < 2; nf++)
            #pragma unroll
            for (int s = 0; s < 2; s++)
                b0[nf][s] = ld_frag(Bso, wn * 64 + nf * 16 + r15, s, quad, r7);
        __builtin_amdgcn_sched_barrier(0);
        __builtin_amdgcn_s_barrier();
        __builtin_amdgcn_sched_barrier(0);
    }

    // ---- epilogue ----
    #pragma unroll
    for (int mf = 0; mf < 8; mf++) {
        #pragma unroll
        for (int r = 0; r < 4; r++) {
            const size_t row = (size_t)(bm + wm * 128 + mf * 16 + quad * 4 + r);
            #pragma unroll
            for (int nf = 0; nf < 4; nf++) {
                const size_t col = (size_t)(bn + wn * 64 + nf * 16 + r15);
                Cmat[row * D_MODEL + col] = (__bf16)acc[mf][nf][r];
            }
        }
    }
}

// ---------------------------------------------------------------------------
// Split-K GEMM for the final projection (fp32 atomic epilogue), BK=32 dbuf.
// ---------------------------------------------------------------------------
__global__ __launch_bounds__(256) void gemm_bt_splitk_kernel(
    const __bf16* __restrict__ A, const __bf16* __restrict__ Bm, float* __restrict__ C)
{
    constexpr int BM = 128, BK = 32, KD = D_MODEL, NIT = (KD / 2) / BK;
    __shared__ __align__(16) __bf16 As[2][BM * BK];
    __shared__ __align__(16) __bf16 Bs[2][BM * BK];

    const int lane = threadIdx.x & 63;
    const int wave = threadIdx.x >> 6;
    const int r15  = lane & 15;
    const int quad = lane >> 4;
    const int bm = blockIdx.x * BM;
    const int bn = blockIdx.y * BM;
    const int wm = (wave >> 1) * 64;
    const int wn = (wave & 1) * 64;
    const int kbase = blockIdx.z * (KD / 2);

    f32x4 acc[4][4] = {};
    const int srow = wave * 32 + (lane >> 2);
    const int sg   = (lane & 3) ^ ((lane >> 2) & 3);

    const __bf16* Arow0 = A  + (size_t)(bm + srow)      * KD + kbase + sg * 8;
    const __bf16* Arow1 = A  + (size_t)(bm + srow + 16) * KD + kbase + sg * 8;
    const __bf16* Brow0 = Bm + (size_t)(bn + srow)      * KD + kbase + sg * 8;
    const __bf16* Brow1 = Bm + (size_t)(bn + srow + 16) * KD + kbase + sg * 8;

    async_copy16(Arow0, &As[0][wave * 1024]);
    async_copy16(Arow1, &As[0][wave * 1024 + 512]);
    async_copy16(Brow0, &Bs[0][wave * 1024]);
    async_copy16(Brow1, &Bs[0][wave * 1024 + 512]);

    for (int it = 0; it < NIT; it++) {
        const int buf = it & 1;
        __syncthreads();

        if (it + 1 < NIT) {
            const int k0 = (it + 1) * BK;
            const int nb = buf ^ 1;
            async_copy16(Arow0 + k0, &As[nb][wave * 1024]);
            async_copy16(Arow1 + k0, &As[nb][wave * 1024 + 512]);
            async_copy16(Brow0 + k0, &Bs[nb][wave * 1024]);
            async_copy16(Brow1 + k0, &Bs[nb][wave * 1024 + 512]);
        }

        bf16x8 av[4], bv[4];
        #pragma unroll
        for (int mt = 0; mt < 4; mt++)
            av[mt] = *(const bf16x8*)&As[buf][(wm + mt * 16 + r15) * BK + ((quad ^ (r15 & 3)) << 3)];
        #pragma unroll
        for (int nt = 0; nt < 4; nt++)
            bv[nt] = *(const bf16x8*)&Bs[buf][(wn + nt * 16 + r15) * BK + ((quad ^ (r15 & 3)) << 3)];
        #pragma unroll
        for (int mt = 0; mt < 4; mt++)
            #pragma unroll
            for (int nt = 0; nt < 4; nt++)
                acc[mt][nt] = __builtin_amdgcn_mfma_f32_16x16x32_bf16(av[mt], bv[nt], acc[mt][nt], 0, 0, 0);
    }

    #pragma unroll
    for (int mt = 0; mt < 4; mt++) {
        #pragma unroll
        for (int r = 0; r < 4; r++) {
            size_t row = bm + wm + mt * 16 + quad * 4 + r;
            #pragma unroll
            for (int nt = 0; nt < 4; nt++) {
                size_t col = bn + wn + nt * 16 + r15;
                atomicAdd(&C[row * D_MODEL + col], acc[mt][nt][r]);
            }
        }
    }
}

// ---------------------------------------------------------------------------
// Preproc q/k: conv(K=4)+SiLU+RMSNorm+RoPE, pure-register.
// q pre-scaled by 1/sqrt(HD); outer rotary negation dropped (cancels in qk^T).
// ---------------------------------------------------------------------------
__global__ __launch_bounds__(256) void preproc_qk_kernel(
    const __bf16* __restrict__ q_raw, const __bf16* __restrict__ k_raw,
    const float* __restrict__ cwq, const float* __restrict__ cwk,
    const float* __restrict__ qnw, const float* __restrict__ knw,
    const float* __restrict__ cosb, const float* __restrict__ sinb,
    __bf16* __restrict__ q_proc, __bf16* __restrict__ k_proc)
{
    const int t = blockIdx.x;
    const int which = blockIdx.y;
    const __bf16* X = which ? k_raw : q_raw;
    const float*  W = which ? cwk : cwq;
    const float*  nw = which ? knw : qnw;
    __bf16* P = which ? k_proc : q_proc;
    const float SC = which ? 1.0f : 0.08838834764831845f;  // 1/sqrt(128) folded into q

    const int tid = threadIdx.x;
    const int c0  = tid * 8;
    const int h   = tid >> 4;
    const int dl0 = (tid & 15) * 8;

    f32x4 wv[8];
    #pragma unroll
    for (int i = 0; i < 8; i++) wv[i] = *(const f32x4*)&W[(c0 + i) * 4];

    float acc[8] = {};
    #pragma unroll
    for (int j = 0; j < 4; j++) {
        int tt = t + j - 3;
        if (tt >= 0) {
            bf16x8 xv = *(const bf16x8*)&X[(size_t)tt * D_MODEL + c0];
            #pragma unroll
            for (int i = 0; i < 8; i++) acc[i] += (float)xv[i] * wv[i][j];
        }
    }
    float sil[8], ss = 0.f;
    #pragma unroll
    for (int i = 0; i < 8; i++) {
        float s = acc[i] / (1.f + __expf(-acc[i]));
        sil[i] = s; ss += s * s;
    }
    #pragma unroll
    for (int off = 1; off < 16; off <<= 1) ss += __shfl_xor(ss, off);
    float inv = rsqrtf(ss * (1.f / 128.f) + 1e-5f);

    f32x4 nv0 = *(const f32x4*)&nw[dl0];
    f32x4 nv1 = *(const f32x4*)&nw[dl0 + 4];
    float yn[8];
    #pragma unroll
    for (int i = 0; i < 8; i++) yn[i] = sil[i] * inv * (i < 4 ? nv0[i] : nv1[i - 4]);

    float partner[8];
    #pragma unroll
    for (int i = 0; i < 8; i++) partner[i] = __shfl_xor(yn[i], 4);  // dl ^ 32

    bf16x8 o;
    if (dl0 < RD_ROT) {
        f32x4 cv0 = *(const f32x4*)&cosb[t * RD_ROT + dl0];
        f32x4 cv1 = *(const f32x4*)&cosb[t * RD_ROT + dl0 + 4];
        f32x4 sv0 = *(const f32x4*)&sinb[t * RD_ROT + dl0];
        f32x4 sv1 = *(const f32x4*)&sinb[t * RD_ROT + dl0 + 4];
        #pragma unroll
        for (int i = 0; i < 8; i++) {
            int dl = dl0 + i;
            float c = i < 4 ? cv0[i] : cv1[i - 4];
            float s = i < 4 ? sv0[i] : sv1[i - 4];
            float rot = (dl < 32) ? -partner[i] : partner[i];  // rotate_half
            o[i] = (__bf16)((yn[i] * c + rot * s) * SC);
        }
    } else {
        #pragma unroll
        for (int i = 0; i < 8; i++) o[i] = (__bf16)(yn[i] * SC);
    }
    *(bf16x8*)&P[((size_t)h * T_SEQ + t) * HDIM + dl0] = o;
}

// ---------------------------------------------------------------------------
// Preproc v: conv+SiLU, transposed (H, HD, T) store, bf16x8 per thread.
// ---------------------------------------------------------------------------
__global__ __launch_bounds__(128) void preproc_v_kernel(
    const __bf16* __restrict__ v_raw, const float* __restrict__ cwv,
    __bf16* __restrict__ v_t)
{
    const int t0 = blockIdx.x * 8;
    const int h = blockIdx.y;
    const int dl = threadIdx.x;
    const int d = h * HDIM + dl;

    f32x4 wv = *(const f32x4*)&cwv[d * 4];
    float x[11];
    #pragma unroll
    for (int m = 0; m < 11; m++) {
        int tt = t0 - 3 + m;
        x[m] = (tt >= 0) ? (float)v_raw[(size_t)tt * D_MODEL + d] : 0.f;
    }
    bf16x8 o;
    #pragma unroll
    for (int r = 0; r < 8; r++) {
        float y = x[r] * wv[0] + x[r + 1] * wv[1] + x[r + 2] * wv[2] + x[r + 3] * wv[3];
        o[r] = (__bf16)(y / (1.f + __expf(-y)));
    }
    *(bf16x8*)&v_t[((size_t)h * HDIM + dl) * T_SEQ + t0] = o;
}

// ---------------------------------------------------------------------------
// Flash attention, causal — 4 waves x 16 q-rows, double-buffered K/V staging,
// STATIC-MAX softmax (q,k RMS-normed + RoPE norm-preserving + folded 1/sqrt(128)
// => |s| <= 11.4, exp safe). Zero cross-lane ops in the k-loop.
// ---------------------------------------------------------------------------
__global__ __launch_bounds__(256, 2) void attn_kernel(
    const __bf16* __restrict__ Qp,   // (H, T, HD), pre-scaled
    const __bf16* __restrict__ Kp,   // (H, T, HD)
    const __bf16* __restrict__ Vt,   // (H, HD, T)
    __bf16* __restrict__ Op)         // (T, D)
{
    constexpr int TK = 64, PSTR = 72;
    __shared__ __align__(16) __bf16 Ks[2][TK * HDIM];   // 2 x 16 KB
    __shared__ __align__(16) __bf16 Vs[2][HDIM * TK];   // 2 x 16 KB
    __shared__ __align__(16) __bf16 Ps[64 * PSTR];      // 9 KB

    const int lane = threadIdx.x & 63;
    const int wave = threadIdx.x >> 6;
    const int r15  = lane & 15;
    const int quad = lane >> 4;
    const int h = blockIdx.y;
    const int qi = (blockIdx.y & 8) ? ((int)gridDim.x - 1 - (int)blockIdx.x) : (int)blockIdx.x;
    const int q0 = qi * TK;

    const __bf16* Kb = Kp + (size_t)h * T_SEQ * HDIM;
    const __bf16* Vb = Vt + (size_t)h * HDIM * T_SEQ;

    const int kchunk = wave * 4;
    const int krow_l = (lane >> 4);
    const int kg     = lane & 15;
    const int vrow_l = (lane >> 3);
    const int vg     = lane & 7;

    bf16x8 qf[4];
    const __bf16* qbase = Qp + ((size_t)h * T_SEQ + q0 + wave * 16 + r15) * HDIM;
    #pragma unroll
    for (int s = 0; s < 4; s++) qf[s] = *(const bf16x8*)(qbase + s * 32 + quad * 8);

    f32x4 oacc[8] = {};
    float lsum[4] = {};

    const int ntk = qi + 1;

    #pragma unroll
    for (int i = 0; i < 4; i++) {
        int ck = kchunk + i;
        int krow = ck * 4 + krow_l;
        int vrow = ck * 8 + vrow_l;
        async_copy16(Kb + (size_t)krow * HDIM + (kg ^ (krow & 15)) * 8, &Ks[0][ck * 512]);
        async_copy16(Vb + (size_t)vrow * T_SEQ + (vg ^ (vrow & 7)) * 8, &Vs[0][ck * 512]);
    }

    for (int it = 0; it < ntk; it++) {
        const int buf = it & 1;
        const bool last = (it == ntk - 1);
        __syncthreads();

        if (!last) {
            const int tkn = (it + 1) * TK;
            const int nbuf = buf ^ 1;
            #pragma unroll
            for (int i = 0; i < 4; i++) {
                int ck = kchunk + i;
                int krow = ck * 4 + krow_l;
                int vrow = ck * 8 + vrow_l;
                async_copy16(Kb + (size_t)(tkn + krow) * HDIM + (kg ^ (krow & 15)) * 8, &Ks[nbuf][ck * 512]);
                async_copy16(Vb + (size_t)vrow * T_SEQ + tkn + (vg ^ (vrow & 7)) * 8, &Vs[nbuf][ck * 512]);
            }
        }

        // ---- S = Q K^T ----
        f32x4 sacc[4] = {};
        #pragma unroll
        for (int s = 0; s < 4; s++) {
            #pragma unroll
            for (int nt = 0; nt < 4; nt++) {
                bf16x8 kf = *(const bf16x8*)&Ks[buf][(nt * 16 + r15) * HDIM + (((s * 4 + quad) ^ r15) << 3)];
                sacc[nt] = __builtin_amdgcn_mfma_f32_16x16x32_bf16(qf[s], kf, sacc[nt], 0, 0, 0);
            }
        }

        // ---- p = exp(s), static max; mask only on the diagonal tile ----
        #pragma unroll
        for (int nt = 0; nt < 4; nt++) {
            #pragma unroll
            for (int r = 0; r < 4; r++) {
                float p = __expf(sacc[nt][r]);
                if (last) {
                    int qrow = q0 + wave * 16 + quad * 4 + r;
                    int kcol = it * TK + nt * 16 + r15;
                    if (kcol > qrow) p = 0.f;
                }
                sacc[nt][r] = p;
                lsum[r] += p;
            }
        }

        // ---- P: C-layout -> LDS (wave-private rows, no barrier) ----
        #pragma unroll
        for (int nt = 0; nt < 4; nt++)
            #pragma unroll
            for (int r = 0; r < 4; r++)
                Ps[(wave * 16 + quad * 4 + r) * PSTR + nt * 16 + r15] = (__bf16)sacc[nt][r];

        // ---- O += P V ----
        #pragma unroll
        for (int s2 = 0; s2 < 2; s2++) {
            bf16x8 pf = *(const bf16x8*)&Ps[(wave * 16 + r15) * PSTR + s2 * 32 + quad * 8];
            #pragma unroll
            for (int nt = 0; nt < 8; nt++) {
                bf16x8 vf = *(const bf16x8*)&Vs[buf][(nt * 16 + r15) * TK + (((s2 * 4 + quad) ^ (r15 & 7)) << 3)];
                oacc[nt] = __builtin_amdgcn_mfma_f32_16x16x32_bf16(pf, vf, oacc[nt], 0, 0, 0);
            }
        }
    }

    #pragma unroll
    for (int r = 0; r < 4; r++) {
        float l = lsum[r];
        #pragma unroll
        for (int off = 1; off < 16; off <<= 1) l += __shfl_xor(l, off);
        float inv = 1.0f / l;
        size_t row = q0 + wave * 16 + quad * 4 + r;
        #pragma unroll
        for (int nt = 0; nt < 8; nt++)
            Op[row * D_MODEL + h * HDIM + nt * 16 + r15] = (__bf16)(oacc[nt][r] * inv);
    }
}

// ---------------------------------------------------------------------------
extern "C" void kernel_launch(void* const* d_in, const int* in_sizes, int n_in,
                              void* d_out, int out_size, void* d_ws, size_t ws_size,
                              hipStream_t stream) {
    (void)in_sizes; (void)n_in; (void)out_size; (void)ws_size;
    const float* hidden = (const float*)d_in[0];
    const float* cosb   = (const float*)d_in[1];
    const float* sinb   = (const float*)d_in[2];
    const float* Wq     = (const float*)d_in[3];
    const float* Wk     = (const float*)d_in[4];
    const float* Wv     = (const float*)d_in[5];
    const float* Wo     = (const float*)d_in[6];
    const float* cwq    = (const float*)d_in[7];
    const float* cwk    = (const float*)d_in[8];
    const float* cwv    = (const float*)d_in[9];
    const float* qnw    = (const float*)d_in[10];
    const float* knw    = (const float*)d_in[11];

    const size_t NEL = (size_t)T_SEQ * D_MODEL;
    __bf16* ws = (__bf16*)d_ws;
    __bf16* h_bf   = ws + 0 * NEL;   // later reused as attn_b
    __bf16* Wq_bf  = ws + 1 * NEL;   // later reused as q_proc
    __bf16* Wk_bf  = ws + 2 * NEL;   // later reused as k_proc
    __bf16* Wv_bf  = ws + 3 * NEL;   // later reused as v_t
    __bf16* Wo_bf  = ws + 4 * NEL;   // persists to final GEMM
    __bf16* q_raw  = ws + 5 * NEL;
    __bf16* k_raw  = ws + 6 * NEL;
    __bf16* v_raw  = ws + 7 * NEL;
    __bf16* q_proc = Wq_bf;
    __bf16* k_proc = Wk_bf;
    __bf16* v_t    = Wv_bf;
    __bf16* attn_b = h_bf;
    float*  out    = (float*)d_out;

    // 0. cast fp32 inputs to bf16
    cast_kernel<<<dim3(T_SEQ, 5), 256, 0, stream>>>(hidden, Wq, Wk, Wv, Wo,
                                                    h_bf, Wq_bf, Wk_bf, Wv_bf, Wo_bf);
    // 1. q,k,v = hidden @ {Wq,Wk,Wv}^T — 256x256 tile, pipelined 4-phase
    gemm_qkv_pipe_kernel<<<dim3(8, 8, 3), 512, 0, stream>>>(
        h_bf, Wq_bf, Wk_bf, Wv_bf, q_raw, k_raw, v_raw);
    // 2. preproc
    preproc_qk_kernel<<<dim3(T_SEQ, 2), 256, 0, stream>>>(
        q_raw, k_raw, cwq, cwk, qnw, knw, cosb, sinb, q_proc, k_proc);
    preproc_v_kernel<<<dim3(T_SEQ / 8, NH), 128, 0, stream>>>(v_raw, cwv, v_t);
    // 3. causal flash attention (dbuf staging + static-max softmax)
    attn_kernel<<<dim3(T_SEQ / 64, NH), 256, 0, stream>>>(q_proc, k_proc, v_t, attn_b);
    // 4. out = attn @ Wo^T, split-K x2 with fp32 atomic epilogue (dbuf)
    hipMemsetAsync(d_out, 0, NEL * sizeof(float), stream);
    gemm_bt_splitk_kernel<<<dim3(16, 16, 2), 256, 0, stream>>>(attn_b, Wo_bf, out);
}

// Round 3
// 323.731 us; speedup vs baseline: 1.0606x; 1.0293x over previous
//
#include <hip/hip_runtime.h>
#include <hip/hip_bf16.h>

// Problem constants (B=1)
#define T_SEQ 2048
#define D_MODEL 2048
#define NH 16
#define HDIM 128
#define RD_ROT 64

typedef __bf16 bf16x8 __attribute__((ext_vector_type(8)));
typedef float f32x4 __attribute__((ext_vector_type(4)));

__device__ __forceinline__ void async_copy16(const __bf16* g, __bf16* l) {
    __builtin_amdgcn_global_load_lds(
        (const __attribute__((address_space(1))) void*)g,
        (__attribute__((address_space(3))) void*)l, 16, 0, 0);
}

// ---------------------------------------------------------------------------
// Cast fp32 -> bf16 for the 5 GEMM operands (hidden, Wq, Wk, Wv, Wo).
// ---------------------------------------------------------------------------
__global__ __launch_bounds__(256) void cast_kernel(
    const float* __restrict__ s0, const float* __restrict__ s1, const float* __restrict__ s2,
    const float* __restrict__ s3, const float* __restrict__ s4,
    __bf16* __restrict__ d0, __bf16* __restrict__ d1, __bf16* __restrict__ d2,
    __bf16* __restrict__ d3, __bf16* __restrict__ d4)
{
    const float* s; __bf16* d;
    switch (blockIdx.y) {
        case 0: s = s0; d = d0; break;
        case 1: s = s1; d = d1; break;
        case 2: s = s2; d = d2; break;
        case 3: s = s3; d = d3; break;
        default: s = s4; d = d4; break;
    }
    size_t base = (size_t)blockIdx.x * D_MODEL + (size_t)threadIdx.x * 8;
    f32x4 a = *(const f32x4*)(s + base);
    f32x4 b = *(const f32x4*)(s + base + 4);
    bf16x8 o;
    #pragma unroll
    for (int i = 0; i < 4; i++) { o[i] = (__bf16)a[i]; o[i + 4] = (__bf16)b[i]; }
    *(bf16x8*)(d + base) = o;
}

// ---------------------------------------------------------------------------
// LDS fragment read: rows are 64 bf16 = 128 B = exactly 32 banks; st_16x32
// XOR swizzle (chunk ^= row&7), realized on the write side by pre-swizzling
// the GLOBAL source of global_load_lds (dest stays linear).
// ---------------------------------------------------------------------------
__device__ __forceinline__ bf16x8 ld_frag(const __bf16* lds, int rr, int s, int quad, int r7) {
    return *(const bf16x8*)&lds[rr * 64 + ((((s << 2) + quad) ^ r7) << 3)];
}

// ---------------------------------------------------------------------------
// QKV GEMM: C = A @ B^T, 256x256 tile, BK=64, 512 threads (8 waves, 2M x 4N).
// Schedule v3 — BALANCED per-phase ds_reads (4/8/8/4), reads issued in phase
// p feed phase p+1's MFMA (counted lgkm by compiler), 1 barrier/phase, drain
// moved to ph2-end so t+1 reads spread over ph3+ph4:
//   ph1: read b1(t)[4]                      | MFMA q1 (a0,b0) | bar
//   ph2: stage B(t+2)->b; read a1(t)[8]     | MFMA q2 (a0,b1) | vmcnt(4) | bar
//   ph3: read a0(t+1)[8]; stage A(t+2)->b   | MFMA q3 (a1,b1) | bar
//   ph4:                                    | MFMA q4 (a1,b0) | read b0(t+1)[4] | bar
// vmcnt(4) at ph2-end: outstanding = [B(t+1),A(t+1) (from t-1 ph2/ph3),
// B(t+2) (this phase)] -> drains t+1 fully, leaves B(t+2) in flight. Barrier
// after the vmcnt makes the drain block-wide. Region safety: buf-b B-region
// reads issue at ph1, stage-write lands >=900cy after ph1's barrier (ds_read
// done in ~120cy) -> safe; A-region read ph2, staged ph3. Tail: t=NT-2 uses
// vmcnt(0) (counted wait would leave A(t+1) undrained); t=NT-1 skips reads.
// ---------------------------------------------------------------------------
__global__ __launch_bounds__(512, 2) void gemm_qkv_pipe_kernel(
    const __bf16* __restrict__ A,
    const __bf16* __restrict__ B0, const __bf16* __restrict__ B1, const __bf16* __restrict__ B2,
    __bf16* __restrict__ C0, __bf16* __restrict__ C1, __bf16* __restrict__ C2)
{
    constexpr int BM = 256, BK = 64, KD = D_MODEL, NT = KD / BK;   // 32 K-tiles

    __shared__ __align__(16) __bf16 As[2][BM * BK];   // 2 x 32 KB
    __shared__ __align__(16) __bf16 Bs[2][BM * BK];   // 2 x 32 KB

    // XCD-aware swizzle over the 192-block grid (192 % 8 == 0 -> bijective)
    const int flat = (int)blockIdx.x + 8 * ((int)blockIdx.y + 8 * (int)blockIdx.z);
    const int swz  = (flat & 7) * 24 + (flat >> 3);
    const int bz   = swz >> 6;
    const int bm   = (swz & 7) * BM;
    const int bn   = ((swz >> 3) & 7) * BM;

    const __bf16* Bmat = bz == 0 ? B0 : (bz == 1 ? B1 : B2);
    __bf16* Cmat       = bz == 0 ? C0 : (bz == 1 ? C1 : C2);

    const int tid  = threadIdx.x;
    const int lane = tid & 63;
    const int wave = tid >> 6;      // 0..7
    const int r15  = lane & 15;
    const int quad = lane >> 4;
    const int r7   = r15 & 7;
    const int wm   = wave >> 2;     // 0..1  : 128-row M half
    const int wn   = wave & 3;      // 0..3  : 64-col  N slice

    // Staging: lane l -> row (l>>3), chunk (l&7); source chunk pre-XORed with
    // row&7 so the linear LDS write realizes the swizzle.
    const int sr8 = lane >> 3;
    const int sck = (lane & 7) ^ sr8;
    const __bf16* Ap = A    + (size_t)(bm + wave * 16 + sr8) * KD + sck * 8;
    const __bf16* Bp = Bmat + (size_t)(bn + wave * 16 + sr8) * KD + sck * 8;

    auto stageA = [&](int buf, int h, int kt) {
        const __bf16* s = Ap + (size_t)(h * 128) * KD + kt;
        __bf16* d = &As[buf][h * 8192 + wave * 1024];
        async_copy16(s, d);
        async_copy16(s + 8 * KD, d + 512);
    };
    auto stageB = [&](int buf, int h, int kt) {
        const __bf16* s = Bp + (size_t)(h * 128) * KD + kt;
        __bf16* d = &Bs[buf][h * 8192 + wave * 1024];
        async_copy16(s, d);
        async_copy16(s + 8 * KD, d + 512);
    };

    f32x4 acc[8][4] = {};   // [M frag 0..7][N frag 0..3]; M1 = +4, N1 = +2
    bf16x8 a0[4][2], a1[4][2], b0[2][2], b1[2][2];

    auto mfma16 = [&](int mb, int nb, bf16x8 (&av)[4][2], bf16x8 (&bv)[2][2]) {
        #pragma unroll
        for (int mf = 0; mf < 4; mf++)
            #pragma unroll
            for (int nf = 0; nf < 2; nf++)
                #pragma unroll
                for (int s = 0; s < 2; s++)
                    acc[mb + mf][nb + nf] =
                        __builtin_amdgcn_mfma_f32_16x16x32_bf16(av[mf][s], bv[nf][s], acc[mb + mf][nb + nf], 0, 0, 0);
    };

    // ---- prologue: stage t0 -> buf0, t1 -> buf1 (slot order B then A) ----
    stageB(0, 0, 0);  stageB(0, 1, 0);  stageA(0, 0, 0);  stageA(0, 1, 0);
    stageB(1, 0, BK); stageB(1, 1, BK); stageA(1, 0, BK); stageA(1, 1, BK);
    asm volatile("s_waitcnt vmcnt(8)" ::: "memory");   // t0 landed, t1 in flight
    __builtin_amdgcn_s_barrier();
    __builtin_amdgcn_sched_barrier(0);
    // q1(t0) operands
    #pragma unroll
    for (int mf = 0; mf < 4; mf++)
        #pragma unroll
        for (int s = 0; s < 2; s++)
            a0[mf][s] = ld_frag(As[0], wm * 128 + mf * 16 + r15, s, quad, r7);
    #pragma unroll
    for (int nf = 0; nf < 2; nf++)
        #pragma unroll
        for (int s = 0; s < 2; s++)
            b0[nf][s] = ld_frag(Bs[0], wn * 64 + nf * 16 + r15, s, quad, r7);

    for (int t = 0; t < NT; t++) {
        const int b = t & 1;
        const __bf16* Asb = As[b];
        const __bf16* Bsb = Bs[b];
        const __bf16* Aso = As[b ^ 1];
        const __bf16* Bso = Bs[b ^ 1];
        const bool pf = (t + 2 < NT);
        const bool rd = (t + 1 < NT);
        const int ktp = (t + 2) * BK;

        // ---- ph1: read b1(t) [feeds ph2]; MFMA q1 (a0,b0) ----
        #pragma unroll
        for (int nf = 0; nf < 2; nf++)
            #pragma unroll
            for (int s = 0; s < 2; s++)
                b1[nf][s] = ld_frag(Bsb, wn * 64 + 32 + nf * 16 + r15, s, quad, r7);
        __builtin_amdgcn_sched_barrier(0);
        __builtin_amdgcn_s_setprio(1);
        mfma16(0, 0, a0, b0);
        __builtin_amdgcn_s_setprio(0);
        __builtin_amdgcn_sched_barrier(0);
        __builtin_amdgcn_s_barrier();
        __builtin_amdgcn_sched_barrier(0);

        // ---- ph2: stage B(t+2); read a1(t) [feeds ph3]; MFMA q2 (a0,b1); drain ----
        if (pf) { stageB(b, 0, ktp); stageB(b, 1, ktp); }
        #pragma unroll
        for (int mf = 0; mf < 4; mf++)
            #pragma unroll
            for (int s = 0; s < 2; s++)
                a1[mf][s] = ld_frag(Asb, wm * 128 + 64 + mf * 16 + r15, s, quad, r7);
        __builtin_amdgcn_sched_barrier(0);
        __builtin_amdgcn_s_setprio(1);
        mfma16(0, 2, a0, b1);
        __builtin_amdgcn_s_setprio(0);
        __builtin_amdgcn_sched_barrier(0);
        if (pf) asm volatile("s_waitcnt vmcnt(4)" ::: "memory");   // drain t+1, keep B(t+2) in flight
        else    asm volatile("s_waitcnt vmcnt(0)" ::: "memory");   // tail: counted wait would under-drain
        __builtin_amdgcn_s_barrier();
        __builtin_amdgcn_sched_barrier(0);

        // ---- ph3: read a0(t+1) [feeds ph4/next q1]; stage A(t+2); MFMA q3 (a1,b1) ----
        if (rd)
            #pragma unroll
            for (int mf = 0; mf < 4; mf++)
                #pragma unroll
                for (int s = 0; s < 2; s++)
                    a0[mf][s] = ld_frag(Aso, wm * 128 + mf * 16 + r15, s, quad, r7);
        if (pf) { stageA(b, 0, ktp); stageA(b, 1, ktp); }
        __builtin_amdgcn_sched_barrier(0);
        __builtin_amdgcn_s_setprio(1);
        mfma16(4, 2, a1, b1);
        __builtin_amdgcn_s_setprio(0);
        __builtin_amdgcn_sched_barrier(0);
        __builtin_amdgcn_s_barrier();
        __builtin_amdgcn_sched_barrier(0);

        // ---- ph4: MFMA q4 (a1, old b0); read b0(t+1) [feeds next q1] ----
        __builtin_amdgcn_s_setprio(1);
        mfma16(4, 0, a1, b0);   // consumes old b0 before reassignment below
        __builtin_amdgcn_s_setprio(0);
        __builtin_amdgcn_sched_barrier(0);
        if (rd)
            #pragma unroll
            for (int nf = 0; nf < 2; nf++)
                #pragma unroll
                for (int s = 0; s < 2; s++)
                    b0[nf][s] = ld_frag(Bso, wn * 64 + nf * 16 + r15, s, quad, r7);
        __builtin_amdgcn_sched_barrier(0);
        __builtin_amdgcn_s_barrier();
        __builtin_amdgcn_sched_barrier(0);
    }

    // ---- epilogue ----
    #pragma unroll
    for (int mf = 0; mf < 8; mf++) {
        #pragma unroll
        for (int r = 0; r < 4; r++) {
            const size_t row = (size_t)(bm + wm * 128 + mf * 16 + quad * 4 + r);
            #pragma unroll
            for (int nf = 0; nf < 4; nf++) {
                const size_t col = (size_t)(bn + wn * 64 + nf * 16 + r15);
                Cmat[row * D_MODEL + col] = (__bf16)acc[mf][nf][r];
            }
        }
    }
}

// ---------------------------------------------------------------------------
// Projection GEMM: out = attn @ Wo^T, fp32 direct stores. 128x128 tile, BK=64,
// 256 threads (4 waves, 2x2), grid 16x16 = 256 blocks (full CU fill, XCD
// swizzle). Same v3 pipelined 4-phase schedule, reads 4/4/4/4 per phase.
// Replaces split-K + memset + 8.4M fp32 atomics.
// ---------------------------------------------------------------------------
__global__ __launch_bounds__(256) void proj_gemm_kernel(
    const __bf16* __restrict__ A, const __bf16* __restrict__ Bmat, float* __restrict__ C)
{
    constexpr int BM = 128, BK = 64, KD = D_MODEL, NT = KD / BK;   // 32 K-tiles

    __shared__ __align__(16) __bf16 As[2][BM * BK];   // 2 x 16 KB
    __shared__ __align__(16) __bf16 Bs[2][BM * BK];   // 2 x 16 KB

    // XCD swizzle over 256 blocks (256 % 8 == 0 -> bijective)
    const int flat = (int)blockIdx.x + 16 * (int)blockIdx.y;
    const int swz  = (flat & 7) * 32 + (flat >> 3);
    const int bm   = (swz & 15) * BM;
    const int bn   = (swz >> 4) * BM;

    const int tid  = threadIdx.x;
    const int lane = tid & 63;
    const int wave = tid >> 6;      // 0..3
    const int r15  = lane & 15;
    const int quad = lane >> 4;
    const int r7   = r15 & 7;
    const int wm   = (wave >> 1) * 64;
    const int wn   = (wave & 1) * 64;

    const int sr8 = lane >> 3;
    const int sck = (lane & 7) ^ sr8;
    const __bf16* Ap = A    + (size_t)(bm + wave * 8 + sr8) * KD + sck * 8;
    const __bf16* Bp = Bmat + (size_t)(bn + wave * 8 + sr8) * KD + sck * 8;

    auto stageA = [&](int buf, int kt) {
        #pragma unroll
        for (int j = 0; j < 4; j++)
            async_copy16(Ap + (size_t)(j * 32) * KD + kt, &As[buf][wave * 512 + j * 2048]);
    };
    auto stageB = [&](int buf, int kt) {
        #pragma unroll
        for (int j = 0; j < 4; j++)
            async_copy16(Bp + (size_t)(j * 32) * KD + kt, &Bs[buf][wave * 512 + j * 2048]);
    };

    f32x4 acc[4][4] = {};
    bf16x8 a0[2][2], a1[2][2], b0[2][2], b1[2][2];

    auto mfma8 = [&](int mb, int nb, bf16x8 (&av)[2][2], bf16x8 (&bv)[2][2]) {
        #pragma unroll
        for (int mf = 0; mf < 2; mf++)
            #pragma unroll
            for (int nf = 0; nf < 2; nf++)
                #pragma unroll
                for (int s = 0; s < 2; s++)
                    acc[mb + mf][nb + nf] =
                        __builtin_amdgcn_mfma_f32_16x16x32_bf16(av[mf][s], bv[nf][s], acc[mb + mf][nb + nf], 0, 0, 0);
    };

    // prologue: t0 -> buf0, t1 -> buf1
    stageB(0, 0);  stageA(0, 0);
    stageB(1, BK); stageA(1, BK);
    asm volatile("s_waitcnt vmcnt(8)" ::: "memory");
    __builtin_amdgcn_s_barrier();
    __builtin_amdgcn_sched_barrier(0);
    #pragma unroll
    for (int mf = 0; mf < 2; mf++)
        #pragma unroll
        for (int s = 0; s < 2; s++)
            a0[mf][s] = ld_frag(As[0], wm + mf * 16 + r15, s, quad, r7);
    #pragma unroll
    for (int nf = 0; nf < 2; nf++)
        #pragma unroll
        for (int s = 0; s < 2; s++)
            b0[nf][s] = ld_frag(Bs[0], wn + nf * 16 + r15, s, quad, r7);

    for (int t = 0; t < NT; t++) {
        const int b = t & 1;
        const __bf16* Asb = As[b];
        const __bf16* Bsb = Bs[b];
        const __bf16* Aso = As[b ^ 1];
        const __bf16* Bso = Bs[b ^ 1];
        const bool pf = (t + 2 < NT);
        const bool rd = (t + 1 < NT);
        const int ktp = (t + 2) * BK;

        // ph1: read b1(t); MFMA q1
        #pragma unroll
        for (int nf = 0; nf < 2; nf++)
            #pragma unroll
            for (int s = 0; s < 2; s++)
                b1[nf][s] = ld_frag(Bsb, wn + 32 + nf * 16 + r15, s, quad, r7);
        __builtin_amdgcn_sched_barrier(0);
        __builtin_amdgcn_s_setprio(1);
        mfma8(0, 0, a0, b0);
        __builtin_amdgcn_s_setprio(0);
        __builtin_amdgcn_sched_barrier(0);
        __builtin_amdgcn_s_barrier();
        __builtin_amdgcn_sched_barrier(0);

        // ph2: stage B(t+2); read a1(t); MFMA q2; drain t+1
        if (pf) stageB(b, ktp);
        #pragma unroll
        for (int mf = 0; mf < 2; mf++)
            #pragma unroll
            for (int s = 0; s < 2; s++)
                a1[mf][s] = ld_frag(Asb, wm + 32 + mf * 16 + r15, s, quad, r7);
        __builtin_amdgcn_sched_barrier(0);
        __builtin_amdgcn_s_setprio(1);
        mfma8(0, 2, a0, b1);
        __builtin_amdgcn_s_setprio(0);
        __builtin_amdgcn_sched_barrier(0);
        if (pf) asm volatile("s_waitcnt vmcnt(4)" ::: "memory");
        else    asm volatile("s_waitcnt vmcnt(0)" ::: "memory");
        __builtin_amdgcn_s_barrier();
        __builtin_amdgcn_sched_barrier(0);

        // ph3: read a0(t+1); stage A(t+2); MFMA q3
        if (rd)
            #pragma unroll
            for (int mf = 0; mf < 2; mf++)
                #pragma unroll
                for (int s = 0; s < 2; s++)
                    a0[mf][s] = ld_frag(Aso, wm + mf * 16 + r15, s, quad, r7);
        if (pf) stageA(b, ktp);
        __builtin_amdgcn_sched_barrier(0);
        __builtin_amdgcn_s_setprio(1);
        mfma8(2, 2, a1, b1);
        __builtin_amdgcn_s_setprio(0);
        __builtin_amdgcn_sched_barrier(0);
        __builtin_amdgcn_s_barrier();
        __builtin_amdgcn_sched_barrier(0);

        // ph4: MFMA q4 (old b0); read b0(t+1)
        __builtin_amdgcn_s_setprio(1);
        mfma8(2, 0, a1, b0);
        __builtin_amdgcn_s_setprio(0);
        __builtin_amdgcn_sched_barrier(0);
        if (rd)
            #pragma unroll
            for (int nf = 0; nf < 2; nf++)
                #pragma unroll
                for (int s = 0; s < 2; s++)
                    b0[nf][s] = ld_frag(Bso, wn + nf * 16 + r15, s, quad, r7);
        __builtin_amdgcn_sched_barrier(0);
        __builtin_amdgcn_s_barrier();
        __builtin_amdgcn_sched_barrier(0);
    }

    // epilogue: fp32 direct stores (each output element written exactly once)
    #pragma unroll
    for (int mf = 0; mf < 4; mf++) {
        #pragma unroll
        for (int r = 0; r < 4; r++) {
            const size_t row = (size_t)(bm + wm + mf * 16 + quad * 4 + r);
            #pragma unroll
            for (int nf = 0; nf < 4; nf++) {
                const size_t col = (size_t)(bn + wn + nf * 16 + r15);
                C[row * D_MODEL + col] = acc[mf][nf][r];
            }
        }
    }
}

// ---------------------------------------------------------------------------
// Preproc q/k: conv(K=4)+SiLU+RMSNorm+RoPE, pure-register.
// q pre-scaled by 1/sqrt(HD); outer rotary negation dropped (cancels in qk^T).
// ---------------------------------------------------------------------------
__global__ __launch_bounds__(256) void preproc_qk_kernel(
    const __bf16* __restrict__ q_raw, const __bf16* __restrict__ k_raw,
    const float* __restrict__ cwq, const float* __restrict__ cwk,
    const float* __restrict__ qnw, const float* __restrict__ knw,
    const float* __restrict__ cosb, const float* __restrict__ sinb,
    __bf16* __restrict__ q_proc, __bf16* __restrict__ k_proc)
{
    const int t = blockIdx.x;
    const int which = blockIdx.y;
    const __bf16* X = which ? k_raw : q_raw;
    const float*  W = which ? cwk : cwq;
    const float*  nw = which ? knw : qnw;
    __bf16* P = which ? k_proc : q_proc;
    const float SC = which ? 1.0f : 0.08838834764831845f;  // 1/sqrt(128) folded into q

    const int tid = threadIdx.x;
    const int c0  = tid * 8;
    const int h   = tid >> 4;
    const int dl0 = (tid & 15) * 8;

    f32x4 wv[8];
    #pragma unroll
    for (int i = 0; i < 8; i++) wv[i] = *(const f32x4*)&W[(c0 + i) * 4];

    float acc[8] = {};
    #pragma unroll
    for (int j = 0; j < 4; j++) {
        int tt = t + j - 3;
        if (tt >= 0) {
            bf16x8 xv = *(const bf16x8*)&X[(size_t)tt * D_MODEL + c0];
            #pragma unroll
            for (int i = 0; i < 8; i++) acc[i] += (float)xv[i] * wv[i][j];
        }
    }
    float sil[8], ss = 0.f;
    #pragma unroll
    for (int i = 0; i < 8; i++) {
        float s = acc[i] / (1.f + __expf(-acc[i]));
        sil[i] = s; ss += s * s;
    }
    #pragma unroll
    for (int off = 1; off < 16; off <<= 1) ss += __shfl_xor(ss, off);
    float inv = rsqrtf(ss * (1.f / 128.f) + 1e-5f);

    f32x4 nv0 = *(const f32x4*)&nw[dl0];
    f32x4 nv1 = *(const f32x4*)&nw[dl0 + 4];
    float yn[8];
    #pragma unroll
    for (int i = 0; i < 8; i++) yn[i] = sil[i] * inv * (i < 4 ? nv0[i] : nv1[i - 4]);

    float partner[8];
    #pragma unroll
    for (int i = 0; i < 8; i++) partner[i] = __shfl_xor(yn[i], 4);  // dl ^ 32

    bf16x8 o;
    if (dl0 < RD_ROT) {
        f32x4 cv0 = *(const f32x4*)&cosb[t * RD_ROT + dl0];
        f32x4 cv1 = *(const f32x4*)&cosb[t * RD_ROT + dl0 + 4];
        f32x4 sv0 = *(const f32x4*)&sinb[t * RD_ROT + dl0];
        f32x4 sv1 = *(const f32x4*)&sinb[t * RD_ROT + dl0 + 4];
        #pragma unroll
        for (int i = 0; i < 8; i++) {
            int dl = dl0 + i;
            float c = i < 4 ? cv0[i] : cv1[i - 4];
            float s = i < 4 ? sv0[i] : sv1[i - 4];
            float rot = (dl < 32) ? -partner[i] : partner[i];  // rotate_half
            o[i] = (__bf16)((yn[i] * c + rot * s) * SC);
        }
    } else {
        #pragma unroll
        for (int i = 0; i < 8; i++) o[i] = (__bf16)(yn[i] * SC);
    }
    *(bf16x8*)&P[((size_t)h * T_SEQ + t) * HDIM + dl0] = o;
}

// ---------------------------------------------------------------------------
// Preproc v: conv+SiLU, transposed (H, HD, T) store, bf16x8 per thread.
// ---------------------------------------------------------------------------
__global__ __launch_bounds__(128) void preproc_v_kernel(
    const __bf16* __restrict__ v_raw, const float* __restrict__ cwv,
    __bf16* __restrict__ v_t)
{
    const int t0 = blockIdx.x * 8;
    const int h = blockIdx.y;
    const int dl = threadIdx.x;
    const int d = h * HDIM + dl;

    f32x4 wv = *(const f32x4*)&cwv[d * 4];
    float x[11];
    #pragma unroll
    for (int m = 0; m < 11; m++) {
        int tt = t0 - 3 + m;
        x[m] = (tt >= 0) ? (float)v_raw[(size_t)tt * D_MODEL + d] : 0.f;
    }
    bf16x8 o;
    #pragma unroll
    for (int r = 0; r < 8; r++) {
        float y = x[r] * wv[0] + x[r + 1] * wv[1] + x[r + 2] * wv[2] + x[r + 3] * wv[3];
        o[r] = (__bf16)(y / (1.f + __expf(-y)));
    }
    *(bf16x8*)&v_t[((size_t)h * HDIM + dl) * T_SEQ + t0] = o;
}

// ---------------------------------------------------------------------------
// Flash attention, causal — 4 waves x 16 q-rows, double-buffered K/V staging,
// STATIC-MAX softmax (q,k RMS-normed + RoPE norm-preserving + folded 1/sqrt(128)
// => |s| <= 11.4, exp safe). Zero cross-lane ops in the k-loop.
// ---------------------------------------------------------------------------
__global__ __launch_bounds__(256, 2) void attn_kernel(
    const __bf16* __restrict__ Qp,   // (H, T, HD), pre-scaled
    const __bf16* __restrict__ Kp,   // (H, T, HD)
    const __bf16* __restrict__ Vt,   // (H, HD, T)
    __bf16* __restrict__ Op)         // (T, D)
{
    constexpr int TK = 64, PSTR = 72;
    __shared__ __align__(16) __bf16 Ks[2][TK * HDIM];   // 2 x 16 KB
    __shared__ __align__(16) __bf16 Vs[2][HDIM * TK];   // 2 x 16 KB
    __shared__ __align__(16) __bf16 Ps[64 * PSTR];      // 9 KB

    const int lane = threadIdx.x & 63;
    const int wave = threadIdx.x >> 6;
    const int r15  = lane & 15;
    const int quad = lane >> 4;
    const int h = blockIdx.y;
    const int qi = (blockIdx.y & 8) ? ((int)gridDim.x - 1 - (int)blockIdx.x) : (int)blockIdx.x;
    const int q0 = qi * TK;

    const __bf16* Kb = Kp + (size_t)h * T_SEQ * HDIM;
    const __bf16* Vb = Vt + (size_t)h * HDIM * T_SEQ;

    const int kchunk = wave * 4;
    const int krow_l = (lane >> 4);
    const int kg     = lane & 15;
    const int vrow_l = (lane >> 3);
    const int vg     = lane & 7;

    bf16x8 qf[4];
    const __bf16* qbase = Qp + ((size_t)h * T_SEQ + q0 + wave * 16 + r15) * HDIM;
    #pragma unroll
    for (int s = 0; s < 4; s++) qf[s] = *(const bf16x8*)(qbase + s * 32 + quad * 8);

    f32x4 oacc[8] = {};
    float lsum[4] = {};

    const int ntk = qi + 1;

    #pragma unroll
    for (int i = 0; i < 4; i++) {
        int ck = kchunk + i;
        int krow = ck * 4 + krow_l;
        int vrow = ck * 8 + vrow_l;
        async_copy16(Kb + (size_t)krow * HDIM + (kg ^ (krow & 15)) * 8, &Ks[0][ck * 512]);
        async_copy16(Vb + (size_t)vrow * T_SEQ + (vg ^ (vrow & 7)) * 8, &Vs[0][ck * 512]);
    }

    for (int it = 0; it < ntk; it++) {
        const int buf = it & 1;
        const bool last = (it == ntk - 1);
        __syncthreads();

        if (!last) {
            const int tkn = (it + 1) * TK;
            const int nbuf = buf ^ 1;
            #pragma unroll
            for (int i = 0; i < 4; i++) {
                int ck = kchunk + i;
                int krow = ck * 4 + krow_l;
                int vrow = ck * 8 + vrow_l;
                async_copy16(Kb + (size_t)(tkn + krow) * HDIM + (kg ^ (krow & 15)) * 8, &Ks[nbuf][ck * 512]);
                async_copy16(Vb + (size_t)vrow * T_SEQ + tkn + (vg ^ (vrow & 7)) * 8, &Vs[nbuf][ck * 512]);
            }
        }

        // ---- S = Q K^T ----
        f32x4 sacc[4] = {};
        #pragma unroll
        for (int s = 0; s < 4; s++) {
            #pragma unroll
            for (int nt = 0; nt < 4; nt++) {
                bf16x8 kf = *(const bf16x8*)&Ks[buf][(nt * 16 + r15) * HDIM + (((s * 4 + quad) ^ r15) << 3)];
                sacc[nt] = __builtin_amdgcn_mfma_f32_16x16x32_bf16(qf[s], kf, sacc[nt], 0, 0, 0);
            }
        }

        // ---- p = exp(s), static max; mask only on the diagonal tile ----
        #pragma unroll
        for (int nt = 0; nt < 4; nt++) {
            #pragma unroll
            for (int r = 0; r < 4; r++) {
                float p = __expf(sacc[nt][r]);
                if (last) {
                    int qrow = q0 + wave * 16 + quad * 4 + r;
                    int kcol = it * TK + nt * 16 + r15;
                    if (kcol > qrow) p = 0.f;
                }
                sacc[nt][r] = p;
                lsum[r] += p;
            }
        }

        // ---- P: C-layout -> LDS (wave-private rows, no barrier) ----
        #pragma unroll
        for (int nt = 0; nt < 4; nt++)
            #pragma unroll
            for (int r = 0; r < 4; r++)
                Ps[(wave * 16 + quad * 4 + r) * PSTR + nt * 16 + r15] = (__bf16)sacc[nt][r];

        // ---- O += P V ----
        #pragma unroll
        for (int s2 = 0; s2 < 2; s2++) {
            bf16x8 pf = *(const bf16x8*)&Ps[(wave * 16 + r15) * PSTR + s2 * 32 + quad * 8];
            #pragma unroll
            for (int nt = 0; nt < 8; nt++) {
                bf16x8 vf = *(const bf16x8*)&Vs[buf][(nt * 16 + r15) * TK + (((s2 * 4 + quad) ^ (r15 & 7)) << 3)];
                oacc[nt] = __builtin_amdgcn_mfma_f32_16x16x32_bf16(pf, vf, oacc[nt], 0, 0, 0);
            }
        }
    }

    #pragma unroll
    for (int r = 0; r < 4; r++) {
        float l = lsum[r];
        #pragma unroll
        for (int off = 1; off < 16; off <<= 1) l += __shfl_xor(l, off);
        float inv = 1.0f / l;
        size_t row = q0 + wave * 16 + quad * 4 + r;
        #pragma unroll
        for (int nt = 0; nt < 8; nt++)
            Op[row * D_MODEL + h * HDIM + nt * 16 + r15] = (__bf16)(oacc[nt][r] * inv);
    }
}

// ---------------------------------------------------------------------------
extern "C" void kernel_launch(void* const* d_in, const int* in_sizes, int n_in,
                              void* d_out, int out_size, void* d_ws, size_t ws_size,
                              hipStream_t stream) {
    (void)in_sizes; (void)n_in; (void)out_size; (void)ws_size;
    const float* hidden = (const float*)d_in[0];
    const float* cosb   = (const float*)d_in[1];
    const float* sinb   = (const float*)d_in[2];
    const float* Wq     = (const float*)d_in[3];
    const float* Wk     = (const float*)d_in[4];
    const float* Wv     = (const float*)d_in[5];
    const float* Wo     = (const float*)d_in[6];
    const float* cwq    = (const float*)d_in[7];
    const float* cwk    = (const float*)d_in[8];
    const float* cwv    = (const float*)d_in[9];
    const float* qnw    = (const float*)d_in[10];
    const float* knw    = (const float*)d_in[11];

    const size_t NEL = (size_t)T_SEQ * D_MODEL;
    __bf16* ws = (__bf16*)d_ws;
    __bf16* h_bf   = ws + 0 * NEL;   // later reused as attn_b
    __bf16* Wq_bf  = ws + 1 * NEL;   // later reused as q_proc
    __bf16* Wk_bf  = ws + 2 * NEL;   // later reused as k_proc
    __bf16* Wv_bf  = ws + 3 * NEL;   // later reused as v_t
    __bf16* Wo_bf  = ws + 4 * NEL;   // persists to final GEMM
    __bf16* q_raw  = ws + 5 * NEL;
    __bf16* k_raw  = ws + 6 * NEL;
    __bf16* v_raw  = ws + 7 * NEL;
    __bf16* q_proc = Wq_bf;
    __bf16* k_proc = Wk_bf;
    __bf16* v_t    = Wv_bf;
    __bf16* attn_b = h_bf;
    float*  out    = (float*)d_out;

    // 0. cast fp32 inputs to bf16
    cast_kernel<<<dim3(T_SEQ, 5), 256, 0, stream>>>(hidden, Wq, Wk, Wv, Wo,
                                                    h_bf, Wq_bf, Wk_bf, Wv_bf, Wo_bf);
    // 1. q,k,v = hidden @ {Wq,Wk,Wv}^T — 256x256 tile, balanced 4-phase pipeline
    gemm_qkv_pipe_kernel<<<dim3(8, 8, 3), 512, 0, stream>>>(
        h_bf, Wq_bf, Wk_bf, Wv_bf, q_raw, k_raw, v_raw);
    // 2. preproc
    preproc_qk_kernel<<<dim3(T_SEQ, 2), 256, 0, stream>>>(
        q_raw, k_raw, cwq, cwk, qnw, knw, cosb, sinb, q_proc, k_proc);
    preproc_v_kernel<<<dim3(T_SEQ / 8, NH), 128, 0, stream>>>(v_raw, cwv, v_t);
    // 3. causal flash attention (dbuf staging + static-max softmax)
    attn_kernel<<<dim3(T_SEQ / 64, NH), 256, 0, stream>>>(q_proc, k_proc, v_t, attn_b);
    // 4. out = attn @ Wo^T — 128x128 pipelined, 256 blocks, fp32 direct stores
    //    (no memset, no atomics)
    proj_gemm_kernel<<<dim3(16, 16), 256, 0, stream>>>(attn_b, Wo_bf, out);
}

// Round 4
// 309.761 us; speedup vs baseline: 1.1084x; 1.0451x over previous
//
#include <hip/hip_runtime.h>
#include <hip/hip_bf16.h>

// Problem constants (B=1)
#define T_SEQ 2048
#define D_MODEL 2048
#define NH 16
#define HDIM 128
#define RD_ROT 64

typedef __bf16 bf16x8 __attribute__((ext_vector_type(8)));
typedef float f32x4 __attribute__((ext_vector_type(4)));

__device__ __forceinline__ void async_copy16(const __bf16* g, __bf16* l) {
    __builtin_amdgcn_global_load_lds(
        (const __attribute__((address_space(1))) void*)g,
        (__attribute__((address_space(3))) void*)l, 16, 0, 0);
}

// ---------------------------------------------------------------------------
// Cast fp32 -> bf16 for the 5 GEMM operands (hidden, Wq, Wk, Wv, Wo).
// ---------------------------------------------------------------------------
__global__ __launch_bounds__(256) void cast_kernel(
    const float* __restrict__ s0, const float* __restrict__ s1, const float* __restrict__ s2,
    const float* __restrict__ s3, const float* __restrict__ s4,
    __bf16* __restrict__ d0, __bf16* __restrict__ d1, __bf16* __restrict__ d2,
    __bf16* __restrict__ d3, __bf16* __restrict__ d4)
{
    const float* s; __bf16* d;
    switch (blockIdx.y) {
        case 0: s = s0; d = d0; break;
        case 1: s = s1; d = d1; break;
        case 2: s = s2; d = d2; break;
        case 3: s = s3; d = d3; break;
        default: s = s4; d = d4; break;
    }
    size_t base = (size_t)blockIdx.x * D_MODEL + (size_t)threadIdx.x * 8;
    f32x4 a = *(const f32x4*)(s + base);
    f32x4 b = *(const f32x4*)(s + base + 4);
    bf16x8 o;
    #pragma unroll
    for (int i = 0; i < 4; i++) { o[i] = (__bf16)a[i]; o[i + 4] = (__bf16)b[i]; }
    *(bf16x8*)(d + base) = o;
}

// ---------------------------------------------------------------------------
// LDS fragment read: rows are 64 bf16 = 128 B = exactly 32 banks; st_16x32
// XOR swizzle (chunk ^= row&7), realized on the write side by pre-swizzling
// the GLOBAL source of global_load_lds (dest stays linear).
// ---------------------------------------------------------------------------
__device__ __forceinline__ bf16x8 ld_frag(const __bf16* lds, int rr, int s, int quad, int r7) {
    return *(const bf16x8*)&lds[rr * 64 + ((((s << 2) + quad) ^ r7) << 3)];
}

// ---------------------------------------------------------------------------
// QKV GEMM: C = A @ B^T, 256x256 tile, BK=64, 512 threads (8 waves, 2M x 4N).
// R2 schedule (best measured: 64.2 us). Reads issued in phase p feed phase
// p+1's MFMA, 1 barrier/phase, 1 counted vmcnt/tile at ph3-end:
//   ph1: read b1(t)[4]            | MFMA q1 (a0,b0)                  | bar
//   ph2: read a1(t)[8]            | MFMA q2 (a0,b1)                  | bar
//   ph3: stage B(t+2)->buf b [4]  | MFMA q3 (a1,b1) | vmcnt(4)       | bar
//   ph4: read a0(t+1)[8]; stage A(t+2)->b [4] | MFMA q4 (a1,b0) | read b0(t+1)[4] | bar
// vmcnt(4) at ph3-end drains t+1's stages (issued t-1 ph3/ph4), leaves this
// tile's B(t+2) in flight; barrier makes it block-wide. Tail uses vmcnt(0).
// ---------------------------------------------------------------------------
__global__ __launch_bounds__(512, 2) void gemm_qkv_pipe_kernel(
    const __bf16* __restrict__ A,
    const __bf16* __restrict__ B0, const __bf16* __restrict__ B1, const __bf16* __restrict__ B2,
    __bf16* __restrict__ C0, __bf16* __restrict__ C1, __bf16* __restrict__ C2)
{
    constexpr int BM = 256, BK = 64, KD = D_MODEL, NT = KD / BK;   // 32 K-tiles

    __shared__ __align__(16) __bf16 As[2][BM * BK];   // 2 x 32 KB
    __shared__ __align__(16) __bf16 Bs[2][BM * BK];   // 2 x 32 KB

    // XCD-aware swizzle over the 192-block grid (192 % 8 == 0 -> bijective)
    const int flat = (int)blockIdx.x + 8 * ((int)blockIdx.y + 8 * (int)blockIdx.z);
    const int swz  = (flat & 7) * 24 + (flat >> 3);
    const int bz   = swz >> 6;
    const int bm   = (swz & 7) * BM;
    const int bn   = ((swz >> 3) & 7) * BM;

    const __bf16* Bmat = bz == 0 ? B0 : (bz == 1 ? B1 : B2);
    __bf16* Cmat       = bz == 0 ? C0 : (bz == 1 ? C1 : C2);

    const int tid  = threadIdx.x;
    const int lane = tid & 63;
    const int wave = tid >> 6;      // 0..7
    const int r15  = lane & 15;
    const int quad = lane >> 4;
    const int r7   = r15 & 7;
    const int wm   = wave >> 2;     // 0..1  : 128-row M half
    const int wn   = wave & 3;      // 0..3  : 64-col  N slice

    // Staging: lane l -> row (l>>3), chunk (l&7); source chunk pre-XORed with
    // row&7 so the linear LDS write realizes the swizzle.
    const int sr8 = lane >> 3;
    const int sck = (lane & 7) ^ sr8;
    const __bf16* Ap = A    + (size_t)(bm + wave * 16 + sr8) * KD + sck * 8;
    const __bf16* Bp = Bmat + (size_t)(bn + wave * 16 + sr8) * KD + sck * 8;

    auto stageA = [&](int buf, int h, int kt) {
        const __bf16* s = Ap + (size_t)(h * 128) * KD + kt;
        __bf16* d = &As[buf][h * 8192 + wave * 1024];
        async_copy16(s, d);
        async_copy16(s + 8 * KD, d + 512);
    };
    auto stageB = [&](int buf, int h, int kt) {
        const __bf16* s = Bp + (size_t)(h * 128) * KD + kt;
        __bf16* d = &Bs[buf][h * 8192 + wave * 1024];
        async_copy16(s, d);
        async_copy16(s + 8 * KD, d + 512);
    };

    f32x4 acc[8][4] = {};   // [M frag 0..7][N frag 0..3]; M1 = +4, N1 = +2
    bf16x8 a0[4][2], a1[4][2], b0[2][2], b1[2][2];

    auto mfma16 = [&](int mb, int nb, bf16x8 (&av)[4][2], bf16x8 (&bv)[2][2]) {
        #pragma unroll
        for (int mf = 0; mf < 4; mf++)
            #pragma unroll
            for (int nf = 0; nf < 2; nf++)
                #pragma unroll
                for (int s = 0; s < 2; s++)
                    acc[mb + mf][nb + nf] =
                        __builtin_amdgcn_mfma_f32_16x16x32_bf16(av[mf][s], bv[nf][s], acc[mb + mf][nb + nf], 0, 0, 0);
    };

    // ---- prologue: stage t0 -> buf0, t1 -> buf1 (slot order B then A) ----
    stageB(0, 0, 0);  stageB(0, 1, 0);  stageA(0, 0, 0);  stageA(0, 1, 0);
    stageB(1, 0, BK); stageB(1, 1, BK); stageA(1, 0, BK); stageA(1, 1, BK);
    asm volatile("s_waitcnt vmcnt(8)" ::: "memory");   // t0 landed, t1 in flight
    __builtin_amdgcn_s_barrier();
    __builtin_amdgcn_sched_barrier(0);
    // q1(t0) operands
    #pragma unroll
    for (int mf = 0; mf < 4; mf++)
        #pragma unroll
        for (int s = 0; s < 2; s++)
            a0[mf][s] = ld_frag(As[0], wm * 128 + mf * 16 + r15, s, quad, r7);
    #pragma unroll
    for (int nf = 0; nf < 2; nf++)
        #pragma unroll
        for (int s = 0; s < 2; s++)
            b0[nf][s] = ld_frag(Bs[0], wn * 64 + nf * 16 + r15, s, quad, r7);

    for (int t = 0; t < NT; t++) {
        const int b = t & 1;
        const __bf16* Asb = As[b];
        const __bf16* Bsb = Bs[b];
        const __bf16* Aso = As[b ^ 1];
        const __bf16* Bso = Bs[b ^ 1];
        const bool pf = (t + 2 < NT);
        const int ktp = (t + 2) * BK;

        // ---- ph1: read b1(t) [feeds ph2]; MFMA q1 (a0,b0) ----
        #pragma unroll
        for (int nf = 0; nf < 2; nf++)
            #pragma unroll
            for (int s = 0; s < 2; s++)
                b1[nf][s] = ld_frag(Bsb, wn * 64 + 32 + nf * 16 + r15, s, quad, r7);
        __builtin_amdgcn_sched_barrier(0);
        __builtin_amdgcn_s_setprio(1);
        mfma16(0, 0, a0, b0);
        __builtin_amdgcn_s_setprio(0);
        __builtin_amdgcn_sched_barrier(0);
        __builtin_amdgcn_s_barrier();
        __builtin_amdgcn_sched_barrier(0);

        // ---- ph2: read a1(t) [feeds ph3]; MFMA q2 (a0,b1) ----
        #pragma unroll
        for (int mf = 0; mf < 4; mf++)
            #pragma unroll
            for (int s = 0; s < 2; s++)
                a1[mf][s] = ld_frag(Asb, wm * 128 + 64 + mf * 16 + r15, s, quad, r7);
        __builtin_amdgcn_sched_barrier(0);
        __builtin_amdgcn_s_setprio(1);
        mfma16(0, 2, a0, b1);
        __builtin_amdgcn_s_setprio(0);
        __builtin_amdgcn_sched_barrier(0);
        __builtin_amdgcn_s_barrier();
        __builtin_amdgcn_sched_barrier(0);

        // ---- ph3: stage B(t+2); MFMA q3 (a1,b1); counted vmcnt ----
        if (pf) { stageB(b, 0, ktp); stageB(b, 1, ktp); }
        __builtin_amdgcn_sched_barrier(0);
        __builtin_amdgcn_s_setprio(1);
        mfma16(4, 2, a1, b1);
        __builtin_amdgcn_s_setprio(0);
        __builtin_amdgcn_sched_barrier(0);
        if (pf) asm volatile("s_waitcnt vmcnt(4)" ::: "memory");   // drain t+1's stages
        else    asm volatile("s_waitcnt vmcnt(0)" ::: "memory");   // tail
        __builtin_amdgcn_s_barrier();
        __builtin_amdgcn_sched_barrier(0);

        // ---- ph4: read a0(t+1); stage A(t+2); MFMA q4 (a1,b0); read b0(t+1) ----
        #pragma unroll
        for (int mf = 0; mf < 4; mf++)
            #pragma unroll
            for (int s = 0; s < 2; s++)
                a0[mf][s] = ld_frag(Aso, wm * 128 + mf * 16 + r15, s, quad, r7);
        if (pf) { stageA(b, 0, ktp); stageA(b, 1, ktp); }
        __builtin_amdgcn_sched_barrier(0);
        __builtin_amdgcn_s_setprio(1);
        mfma16(4, 0, a1, b0);   // consumes old b0 before it is overwritten below
        __builtin_amdgcn_s_setprio(0);
        __builtin_amdgcn_sched_barrier(0);
        #pragma unroll
        for (int nf = 0; nf < 2; nf++)
            #pragma unroll
            for (int s = 0; s < 2; s++)
                b0[nf][s] = ld_frag(Bso, wn * 64 + nf * 16 + r15, s, quad, r7);
        __builtin_amdgcn_sched_barrier(0);
        __builtin_amdgcn_s_barrier();
        __builtin_amdgcn_sched_barrier(0);
    }

    // ---- epilogue ----
    #pragma unroll
    for (int mf = 0; mf < 8; mf++) {
        #pragma unroll
        for (int r = 0; r < 4; r++) {
            const size_t row = (size_t)(bm + wm * 128 + mf * 16 + quad * 4 + r);
            #pragma unroll
            for (int nf = 0; nf < 4; nf++) {
                const size_t col = (size_t)(bn + wn * 64 + nf * 16 + r15);
                Cmat[row * D_MODEL + col] = (__bf16)acc[mf][nf][r];
            }
        }
    }
}

// ---------------------------------------------------------------------------
// Projection GEMM: out = attn @ Wo^T, fp32 direct stores. 128x128 tile, BK=64,
// 256 threads (4 waves, 2x2), grid 16x16 = 256 blocks (full CU fill, XCD
// swizzle). v3 pipelined 4-phase schedule, reads 4/4/4/4 per phase.
// ---------------------------------------------------------------------------
__global__ __launch_bounds__(256) void proj_gemm_kernel(
    const __bf16* __restrict__ A, const __bf16* __restrict__ Bmat, float* __restrict__ C)
{
    constexpr int BM = 128, BK = 64, KD = D_MODEL, NT = KD / BK;   // 32 K-tiles

    __shared__ __align__(16) __bf16 As[2][BM * BK];   // 2 x 16 KB
    __shared__ __align__(16) __bf16 Bs[2][BM * BK];   // 2 x 16 KB

    // XCD swizzle over 256 blocks (256 % 8 == 0 -> bijective)
    const int flat = (int)blockIdx.x + 16 * (int)blockIdx.y;
    const int swz  = (flat & 7) * 32 + (flat >> 3);
    const int bm   = (swz & 15) * BM;
    const int bn   = (swz >> 4) * BM;

    const int tid  = threadIdx.x;
    const int lane = tid & 63;
    const int wave = tid >> 6;      // 0..3
    const int r15  = lane & 15;
    const int quad = lane >> 4;
    const int r7   = r15 & 7;
    const int wm   = (wave >> 1) * 64;
    const int wn   = (wave & 1) * 64;

    const int sr8 = lane >> 3;
    const int sck = (lane & 7) ^ sr8;
    const __bf16* Ap = A    + (size_t)(bm + wave * 8 + sr8) * KD + sck * 8;
    const __bf16* Bp = Bmat + (size_t)(bn + wave * 8 + sr8) * KD + sck * 8;

    auto stageA = [&](int buf, int kt) {
        #pragma unroll
        for (int j = 0; j < 4; j++)
            async_copy16(Ap + (size_t)(j * 32) * KD + kt, &As[buf][wave * 512 + j * 2048]);
    };
    auto stageB = [&](int buf, int kt) {
        #pragma unroll
        for (int j = 0; j < 4; j++)
            async_copy16(Bp + (size_t)(j * 32) * KD + kt, &Bs[buf][wave * 512 + j * 2048]);
    };

    f32x4 acc[4][4] = {};
    bf16x8 a0[2][2], a1[2][2], b0[2][2], b1[2][2];

    auto mfma8 = [&](int mb, int nb, bf16x8 (&av)[2][2], bf16x8 (&bv)[2][2]) {
        #pragma unroll
        for (int mf = 0; mf < 2; mf++)
            #pragma unroll
            for (int nf = 0; nf < 2; nf++)
                #pragma unroll
                for (int s = 0; s < 2; s++)
                    acc[mb + mf][nb + nf] =
                        __builtin_amdgcn_mfma_f32_16x16x32_bf16(av[mf][s], bv[nf][s], acc[mb + mf][nb + nf], 0, 0, 0);
    };

    // prologue: t0 -> buf0, t1 -> buf1
    stageB(0, 0);  stageA(0, 0);
    stageB(1, BK); stageA(1, BK);
    asm volatile("s_waitcnt vmcnt(8)" ::: "memory");
    __builtin_amdgcn_s_barrier();
    __builtin_amdgcn_sched_barrier(0);
    #pragma unroll
    for (int mf = 0; mf < 2; mf++)
        #pragma unroll
        for (int s = 0; s < 2; s++)
            a0[mf][s] = ld_frag(As[0], wm + mf * 16 + r15, s, quad, r7);
    #pragma unroll
    for (int nf = 0; nf < 2; nf++)
        #pragma unroll
        for (int s = 0; s < 2; s++)
            b0[nf][s] = ld_frag(Bs[0], wn + nf * 16 + r15, s, quad, r7);

    for (int t = 0; t < NT; t++) {
        const int b = t & 1;
        const __bf16* Asb = As[b];
        const __bf16* Bsb = Bs[b];
        const __bf16* Aso = As[b ^ 1];
        const __bf16* Bso = Bs[b ^ 1];
        const bool pf = (t + 2 < NT);
        const bool rd = (t + 1 < NT);
        const int ktp = (t + 2) * BK;

        // ph1: read b1(t); MFMA q1
        #pragma unroll
        for (int nf = 0; nf < 2; nf++)
            #pragma unroll
            for (int s = 0; s < 2; s++)
                b1[nf][s] = ld_frag(Bsb, wn + 32 + nf * 16 + r15, s, quad, r7);
        __builtin_amdgcn_sched_barrier(0);
        __builtin_amdgcn_s_setprio(1);
        mfma8(0, 0, a0, b0);
        __builtin_amdgcn_s_setprio(0);
        __builtin_amdgcn_sched_barrier(0);
        __builtin_amdgcn_s_barrier();
        __builtin_amdgcn_sched_barrier(0);

        // ph2: stage B(t+2); read a1(t); MFMA q2; drain t+1
        if (pf) stageB(b, ktp);
        #pragma unroll
        for (int mf = 0; mf < 2; mf++)
            #pragma unroll
            for (int s = 0; s < 2; s++)
                a1[mf][s] = ld_frag(Asb, wm + 32 + mf * 16 + r15, s, quad, r7);
        __builtin_amdgcn_sched_barrier(0);
        __builtin_amdgcn_s_setprio(1);
        mfma8(0, 2, a0, b1);
        __builtin_amdgcn_s_setprio(0);
        __builtin_amdgcn_sched_barrier(0);
        if (pf) asm volatile("s_waitcnt vmcnt(4)" ::: "memory");
        else    asm volatile("s_waitcnt vmcnt(0)" ::: "memory");
        __builtin_amdgcn_s_barrier();
        __builtin_amdgcn_sched_barrier(0);

        // ph3: read a0(t+1); stage A(t+2); MFMA q3
        if (rd)
            #pragma unroll
            for (int mf = 0; mf < 2; mf++)
                #pragma unroll
                for (int s = 0; s < 2; s++)
                    a0[mf][s] = ld_frag(Aso, wm + mf * 16 + r15, s, quad, r7);
        if (pf) stageA(b, ktp);
        __builtin_amdgcn_sched_barrier(0);
        __builtin_amdgcn_s_setprio(1);
        mfma8(2, 2, a1, b1);
        __builtin_amdgcn_s_setprio(0);
        __builtin_amdgcn_sched_barrier(0);
        __builtin_amdgcn_s_barrier();
        __builtin_amdgcn_sched_barrier(0);

        // ph4: MFMA q4 (old b0); read b0(t+1)
        __builtin_amdgcn_s_setprio(1);
        mfma8(2, 0, a1, b0);
        __builtin_amdgcn_s_setprio(0);
        __builtin_amdgcn_sched_barrier(0);
        if (rd)
            #pragma unroll
            for (int nf = 0; nf < 2; nf++)
                #pragma unroll
                for (int s = 0; s < 2; s++)
                    b0[nf][s] = ld_frag(Bso, wn + nf * 16 + r15, s, quad, r7);
        __builtin_amdgcn_sched_barrier(0);
        __builtin_amdgcn_s_barrier();
        __builtin_amdgcn_sched_barrier(0);
    }

    // epilogue: fp32 direct stores (each output element written exactly once)
    #pragma unroll
    for (int mf = 0; mf < 4; mf++) {
        #pragma unroll
        for (int r = 0; r < 4; r++) {
            const size_t row = (size_t)(bm + wm + mf * 16 + quad * 4 + r);
            #pragma unroll
            for (int nf = 0; nf < 4; nf++) {
                const size_t col = (size_t)(bn + wn + nf * 16 + r15);
                C[row * D_MODEL + col] = acc[mf][nf][r];
            }
        }
    }
}

// ---------------------------------------------------------------------------
// Preproc q/k: conv(K=4)+SiLU+RMSNorm+RoPE, pure-register.
// q pre-scaled by 1/sqrt(HD); outer rotary negation dropped (cancels in qk^T).
// ---------------------------------------------------------------------------
__global__ __launch_bounds__(256) void preproc_qk_kernel(
    const __bf16* __restrict__ q_raw, const __bf16* __restrict__ k_raw,
    const float* __restrict__ cwq, const float* __restrict__ cwk,
    const float* __restrict__ qnw, const float* __restrict__ knw,
    const float* __restrict__ cosb, const float* __restrict__ sinb,
    __bf16* __restrict__ q_proc, __bf16* __restrict__ k_proc)
{
    const int t = blockIdx.x;
    const int which = blockIdx.y;
    const __bf16* X = which ? k_raw : q_raw;
    const float*  W = which ? cwk : cwq;
    const float*  nw = which ? knw : qnw;
    __bf16* P = which ? k_proc : q_proc;
    const float SC = which ? 1.0f : 0.08838834764831845f;  // 1/sqrt(128) folded into q

    const int tid = threadIdx.x;
    const int c0  = tid * 8;
    const int h   = tid >> 4;
    const int dl0 = (tid & 15) * 8;

    f32x4 wv[8];
    #pragma unroll
    for (int i = 0; i < 8; i++) wv[i] = *(const f32x4*)&W[(c0 + i) * 4];

    float acc[8] = {};
    #pragma unroll
    for (int j = 0; j < 4; j++) {
        int tt = t + j - 3;
        if (tt >= 0) {
            bf16x8 xv = *(const bf16x8*)&X[(size_t)tt * D_MODEL + c0];
            #pragma unroll
            for (int i = 0; i < 8; i++) acc[i] += (float)xv[i] * wv[i][j];
        }
    }
    float sil[8], ss = 0.f;
    #pragma unroll
    for (int i = 0; i < 8; i++) {
        float s = acc[i] / (1.f + __expf(-acc[i]));
        sil[i] = s; ss += s * s;
    }
    #pragma unroll
    for (int off = 1; off < 16; off <<= 1) ss += __shfl_xor(ss, off);
    float inv = rsqrtf(ss * (1.f / 128.f) + 1e-5f);

    f32x4 nv0 = *(const f32x4*)&nw[dl0];
    f32x4 nv1 = *(const f32x4*)&nw[dl0 + 4];
    float yn[8];
    #pragma unroll
    for (int i = 0; i < 8; i++) yn[i] = sil[i] * inv * (i < 4 ? nv0[i] : nv1[i - 4]);

    float partner[8];
    #pragma unroll
    for (int i = 0; i < 8; i++) partner[i] = __shfl_xor(yn[i], 4);  // dl ^ 32

    bf16x8 o;
    if (dl0 < RD_ROT) {
        f32x4 cv0 = *(const f32x4*)&cosb[t * RD_ROT + dl0];
        f32x4 cv1 = *(const f32x4*)&cosb[t * RD_ROT + dl0 + 4];
        f32x4 sv0 = *(const f32x4*)&sinb[t * RD_ROT + dl0];
        f32x4 sv1 = *(const f32x4*)&sinb[t * RD_ROT + dl0 + 4];
        #pragma unroll
        for (int i = 0; i < 8; i++) {
            int dl = dl0 + i;
            float c = i < 4 ? cv0[i] : cv1[i - 4];
            float s = i < 4 ? sv0[i] : sv1[i - 4];
            float rot = (dl < 32) ? -partner[i] : partner[i];  // rotate_half
            o[i] = (__bf16)((yn[i] * c + rot * s) * SC);
        }
    } else {
        #pragma unroll
        for (int i = 0; i < 8; i++) o[i] = (__bf16)(yn[i] * SC);
    }
    *(bf16x8*)&P[((size_t)h * T_SEQ + t) * HDIM + dl0] = o;
}

// ---------------------------------------------------------------------------
// Preproc v: conv+SiLU, transposed (H, HD, T) store, bf16x8 per thread.
// ---------------------------------------------------------------------------
__global__ __launch_bounds__(128) void preproc_v_kernel(
    const __bf16* __restrict__ v_raw, const float* __restrict__ cwv,
    __bf16* __restrict__ v_t)
{
    const int t0 = blockIdx.x * 8;
    const int h = blockIdx.y;
    const int dl = threadIdx.x;
    const int d = h * HDIM + dl;

    f32x4 wv = *(const f32x4*)&cwv[d * 4];
    float x[11];
    #pragma unroll
    for (int m = 0; m < 11; m++) {
        int tt = t0 - 3 + m;
        x[m] = (tt >= 0) ? (float)v_raw[(size_t)tt * D_MODEL + d] : 0.f;
    }
    bf16x8 o;
    #pragma unroll
    for (int r = 0; r < 8; r++) {
        float y = x[r] * wv[0] + x[r + 1] * wv[1] + x[r + 2] * wv[2] + x[r + 3] * wv[3];
        o[r] = (__bf16)(y / (1.f + __expf(-y)));
    }
    *(bf16x8*)&v_t[((size_t)h * HDIM + dl) * T_SEQ + t0] = o;
}

// ---------------------------------------------------------------------------
// Flash attention, causal — 4 waves x 16 q-rows, STATIC-MAX softmax.
// NEW: raw s_barrier + counted vmcnt (no __syncthreads full drain), 2-deep
// staging pipeline: prologue stages tiles 0,1; loop iter `it` stages tile
// it+2 into buf(it) AFTER the post-compute barrier (all waves done reading).
// vmcnt ledger (8 stage ops/wave/tile): at iter top, queue = [stage(it) 8,
// stage(it+1) 8] -> vmcnt(8) drains stage(it), leaves it+1 in flight; last
// iter uses vmcnt(0). Barrier after the vmcnt makes the drain block-wide.
// Read/overwrite safety: every ds_read feeds an MFMA before the barrier
// (compiler lgkm waits => reads retired at barrier arrival); stage writes
// land >=900cy after the post-compute barrier.
// ---------------------------------------------------------------------------
__global__ __launch_bounds__(256, 2) void attn_kernel(
    const __bf16* __restrict__ Qp,   // (H, T, HD), pre-scaled
    const __bf16* __restrict__ Kp,   // (H, T, HD)
    const __bf16* __restrict__ Vt,   // (H, HD, T)
    __bf16* __restrict__ Op)         // (T, D)
{
    constexpr int TK = 64, PSTR = 72;
    __shared__ __align__(16) __bf16 Ks[2][TK * HDIM];   // 2 x 16 KB
    __shared__ __align__(16) __bf16 Vs[2][HDIM * TK];   // 2 x 16 KB
    __shared__ __align__(16) __bf16 Ps[64 * PSTR];      // 9 KB

    const int lane = threadIdx.x & 63;
    const int wave = threadIdx.x >> 6;
    const int r15  = lane & 15;
    const int quad = lane >> 4;
    const int h = blockIdx.y;
    const int qi = (blockIdx.y & 8) ? ((int)gridDim.x - 1 - (int)blockIdx.x) : (int)blockIdx.x;
    const int q0 = qi * TK;

    const __bf16* Kb = Kp + (size_t)h * T_SEQ * HDIM;
    const __bf16* Vb = Vt + (size_t)h * HDIM * T_SEQ;

    const int kchunk = wave * 4;
    const int krow_l = (lane >> 4);
    const int kg     = lane & 15;
    const int vrow_l = (lane >> 3);
    const int vg     = lane & 7;

    auto stage_tile = [&](int tile, int sb) {
        const int tkn = tile * TK;
        #pragma unroll
        for (int i = 0; i < 4; i++) {
            int ck = kchunk + i;
            int krow = ck * 4 + krow_l;
            int vrow = ck * 8 + vrow_l;
            async_copy16(Kb + (size_t)(tkn + krow) * HDIM + (kg ^ (krow & 15)) * 8, &Ks[sb][ck * 512]);
            async_copy16(Vb + (size_t)vrow * T_SEQ + tkn + (vg ^ (vrow & 7)) * 8, &Vs[sb][ck * 512]);
        }
    };

    bf16x8 qf[4];
    const __bf16* qbase = Qp + ((size_t)h * T_SEQ + q0 + wave * 16 + r15) * HDIM;
    #pragma unroll
    for (int s = 0; s < 4; s++) qf[s] = *(const bf16x8*)(qbase + s * 32 + quad * 8);

    f32x4 oacc[8] = {};
    float lsum[4] = {};

    const int ntk = qi + 1;

    // ---- prologue: 2-deep staging ----
    stage_tile(0, 0);
    if (ntk > 1) stage_tile(1, 1);

    for (int it = 0; it < ntk; it++) {
        const int buf = it & 1;
        const bool last = (it == ntk - 1);

        if (last) asm volatile("s_waitcnt vmcnt(0)" ::: "memory");   // only stage(it) left
        else      asm volatile("s_waitcnt vmcnt(8)" ::: "memory");   // drain it, keep it+1 flying
        __builtin_amdgcn_s_barrier();

        // ---- S = Q K^T ----
        f32x4 sacc[4] = {};
        #pragma unroll
        for (int s = 0; s < 4; s++) {
            #pragma unroll
            for (int nt = 0; nt < 4; nt++) {
                bf16x8 kf = *(const bf16x8*)&Ks[buf][(nt * 16 + r15) * HDIM + (((s * 4 + quad) ^ r15) << 3)];
                sacc[nt] = __builtin_amdgcn_mfma_f32_16x16x32_bf16(qf[s], kf, sacc[nt], 0, 0, 0);
            }
        }

        // ---- p = exp(s), static max; mask only on the diagonal tile ----
        #pragma unroll
        for (int nt = 0; nt < 4; nt++) {
            #pragma unroll
            for (int r = 0; r < 4; r++) {
                float p = __expf(sacc[nt][r]);
                if (last) {
                    int qrow = q0 + wave * 16 + quad * 4 + r;
                    int kcol = it * TK + nt * 16 + r15;
                    if (kcol > qrow) p = 0.f;
                }
                sacc[nt][r] = p;
                lsum[r] += p;
            }
        }

        // ---- P: C-layout -> LDS (wave-private rows, no barrier) ----
        #pragma unroll
        for (int nt = 0; nt < 4; nt++)
            #pragma unroll
            for (int r = 0; r < 4; r++)
                Ps[(wave * 16 + quad * 4 + r) * PSTR + nt * 16 + r15] = (__bf16)sacc[nt][r];

        // ---- O += P V ----
        #pragma unroll
        for (int s2 = 0; s2 < 2; s2++) {
            bf16x8 pf = *(const bf16x8*)&Ps[(wave * 16 + r15) * PSTR + s2 * 32 + quad * 8];
            #pragma unroll
            for (int nt = 0; nt < 8; nt++) {
                bf16x8 vf = *(const bf16x8*)&Vs[buf][(nt * 16 + r15) * TK + (((s2 * 4 + quad) ^ (r15 & 7)) << 3)];
                oacc[nt] = __builtin_amdgcn_mfma_f32_16x16x32_bf16(pf, vf, oacc[nt], 0, 0, 0);
            }
        }

        // ---- post-compute barrier, then stage it+2 into this buf ----
        __builtin_amdgcn_s_barrier();
        if (it + 2 < ntk) stage_tile(it + 2, buf);
    }

    #pragma unroll
    for (int r = 0; r < 4; r++) {
        float l = lsum[r];
        #pragma unroll
        for (int off = 1; off < 16; off <<= 1) l += __shfl_xor(l, off);
        float inv = 1.0f / l;
        size_t row = q0 + wave * 16 + quad * 4 + r;
        #pragma unroll
        for (int nt = 0; nt < 8; nt++)
            Op[row * D_MODEL + h * HDIM + nt * 16 + r15] = (__bf16)(oacc[nt][r] * inv);
    }
}

// ---------------------------------------------------------------------------
extern "C" void kernel_launch(void* const* d_in, const int* in_sizes, int n_in,
                              void* d_out, int out_size, void* d_ws, size_t ws_size,
                              hipStream_t stream) {
    (void)in_sizes; (void)n_in; (void)out_size; (void)ws_size;
    const float* hidden = (const float*)d_in[0];
    const float* cosb   = (const float*)d_in[1];
    const float* sinb   = (const float*)d_in[2];
    const float* Wq     = (const float*)d_in[3];
    const float* Wk     = (const float*)d_in[4];
    const float* Wv     = (const float*)d_in[5];
    const float* Wo     = (const float*)d_in[6];
    const float* cwq    = (const float*)d_in[7];
    const float* cwk    = (const float*)d_in[8];
    const float* cwv    = (const float*)d_in[9];
    const float* qnw    = (const float*)d_in[10];
    const float* knw    = (const float*)d_in[11];

    const size_t NEL = (size_t)T_SEQ * D_MODEL;
    __bf16* ws = (__bf16*)d_ws;
    __bf16* h_bf   = ws + 0 * NEL;   // later reused as attn_b
    __bf16* Wq_bf  = ws + 1 * NEL;   // later reused as q_proc
    __bf16* Wk_bf  = ws + 2 * NEL;   // later reused as k_proc
    __bf16* Wv_bf  = ws + 3 * NEL;   // later reused as v_t
    __bf16* Wo_bf  = ws + 4 * NEL;   // persists to final GEMM
    __bf16* q_raw  = ws + 5 * NEL;
    __bf16* k_raw  = ws + 6 * NEL;
    __bf16* v_raw  = ws + 7 * NEL;
    __bf16* q_proc = Wq_bf;
    __bf16* k_proc = Wk_bf;
    __bf16* v_t    = Wv_bf;
    __bf16* attn_b = h_bf;
    float*  out    = (float*)d_out;

    // 0. cast fp32 inputs to bf16
    cast_kernel<<<dim3(T_SEQ, 5), 256, 0, stream>>>(hidden, Wq, Wk, Wv, Wo,
                                                    h_bf, Wq_bf, Wk_bf, Wv_bf, Wo_bf);
    // 1. q,k,v = hidden @ {Wq,Wk,Wv}^T — R2 pipelined 4-phase (best measured)
    gemm_qkv_pipe_kernel<<<dim3(8, 8, 3), 512, 0, stream>>>(
        h_bf, Wq_bf, Wk_bf, Wv_bf, q_raw, k_raw, v_raw);
    // 2. preproc
    preproc_qk_kernel<<<dim3(T_SEQ, 2), 256, 0, stream>>>(
        q_raw, k_raw, cwq, cwk, qnw, knw, cosb, sinb, q_proc, k_proc);
    preproc_v_kernel<<<dim3(T_SEQ / 8, NH), 128, 0, stream>>>(v_raw, cwv, v_t);
    // 3. causal flash attention — raw barriers + counted vmcnt, 2-deep staging
    attn_kernel<<<dim3(T_SEQ / 64, NH), 256, 0, stream>>>(q_proc, k_proc, v_t, attn_b);
    // 4. out = attn @ Wo^T — 128x128 pipelined, 256 blocks, fp32 direct stores
    proj_gemm_kernel<<<dim3(16, 16), 256, 0, stream>>>(attn_b, Wo_bf, out);
}

// Round 5
// 305.236 us; speedup vs baseline: 1.1248x; 1.0148x over previous
//
#include <hip/hip_runtime.h>
#include <hip/hip_bf16.h>

// Problem constants (B=1)
#define T_SEQ 2048
#define D_MODEL 2048
#define NH 16
#define HDIM 128
#define RD_ROT 64

typedef __bf16 bf16x8 __attribute__((ext_vector_type(8)));
typedef float f32x4 __attribute__((ext_vector_type(4)));

__device__ __forceinline__ void async_copy16(const __bf16* g, __bf16* l) {
    __builtin_amdgcn_global_load_lds(
        (const __attribute__((address_space(1))) void*)g,
        (__attribute__((address_space(3))) void*)l, 16, 0, 0);
}

// ---------------------------------------------------------------------------
// Cast fp32 -> bf16 for the 5 GEMM operands (hidden, Wq, Wk, Wv, Wo).
// ---------------------------------------------------------------------------
__global__ __launch_bounds__(256) void cast_kernel(
    const float* __restrict__ s0, const float* __restrict__ s1, const float* __restrict__ s2,
    const float* __restrict__ s3, const float* __restrict__ s4,
    __bf16* __restrict__ d0, __bf16* __restrict__ d1, __bf16* __restrict__ d2,
    __bf16* __restrict__ d3, __bf16* __restrict__ d4)
{
    const float* s; __bf16* d;
    switch (blockIdx.y) {
        case 0: s = s0; d = d0; break;
        case 1: s = s1; d = d1; break;
        case 2: s = s2; d = d2; break;
        case 3: s = s3; d = d3; break;
        default: s = s4; d = d4; break;
    }
    size_t base = (size_t)blockIdx.x * D_MODEL + (size_t)threadIdx.x * 8;
    f32x4 a = *(const f32x4*)(s + base);
    f32x4 b = *(const f32x4*)(s + base + 4);
    bf16x8 o;
    #pragma unroll
    for (int i = 0; i < 4; i++) { o[i] = (__bf16)a[i]; o[i + 4] = (__bf16)b[i]; }
    *(bf16x8*)(d + base) = o;
}

// ---------------------------------------------------------------------------
// LDS fragment read: rows are 64 bf16 = 128 B = exactly 32 banks; st_16x32
// XOR swizzle (chunk ^= row&7), realized on the write side by pre-swizzling
// the GLOBAL source of global_load_lds (dest stays linear).
// ---------------------------------------------------------------------------
__device__ __forceinline__ bf16x8 ld_frag(const __bf16* lds, int rr, int s, int quad, int r7) {
    return *(const bf16x8*)&lds[rr * 64 + ((((s << 2) + quad) ^ r7) << 3)];
}

// ---------------------------------------------------------------------------
// FUSED QKV GEMM: C = A @ Bf^T where Bf = [Wq;Wk;Wv] (6144x2048, contiguous
// in workspace) and C = [q_raw;k_raw;v_raw] (contiguous). BM=256, BN=192,
// BK=64 -> grid 8 x 32 = 256 blocks = EXACTLY 1 block/CU (R4's 75%-fill fix).
// blockIdx.x = mtile = XCD id (natural dispatch round-robins x over XCDs), so
// each XCD keeps one 1MB A-panel L2-resident.
// 512 threads, 8 waves (2M x 4N): per-wave 128 x 48 (Mfrag 8, Nfrag 3).
// 2-phase pipelined schedule (reads in phase p feed phase p+1):
//   ph1: read a1(t)[8]; stage B(t+2)[3] | MFMA q1 = a0 x b(t) [24]
//        | vmcnt(3) (drain t+1, keep B(t+2)) | bar
//   ph2: read b(t+1)[6] + a0(t+1)[8]; stage A(t+2)[4]
//        | MFMA q2 = a1 x b(t) [24] | bar
// Ledger: stages/tile = B:3 (ph1) + A:4 (ph2). At ph1(t)-end outstanding =
// B(t+1)[3] ... wait, B(t+1) drained at ph1(t-1); = A(t+1)[4] + B(t+2)[3]
// -> vmcnt(3) drains A(t+1), leaves B(t+2). Tails (t>=NT-2): vmcnt(0).
// b-registers double-banked (bE/bO) via 2x loop unroll so b(t+1) reads don't
// clobber b(t) while q2 consumes it.
// ---------------------------------------------------------------------------
__global__ __launch_bounds__(512, 2) void gemm_qkv_fused_kernel(
    const __bf16* __restrict__ A,      // 2048 x 2048
    const __bf16* __restrict__ Bf,     // 6144 x 2048 (Wq;Wk;Wv)
    __bf16* __restrict__ Cf)           // 3 x (2048 x 2048) contiguous
{
    constexpr int BM = 256, BN = 192, BK = 64, KD = D_MODEL, NT = KD / BK;  // 32

    __shared__ __align__(16) __bf16 As[2][BM * BK];   // 2 x 32 KB
    __shared__ __align__(16) __bf16 Bs[2][BN * BK];   // 2 x 24 KB   (112 KB total)

    const int bm = (int)blockIdx.x * BM;      // mtile 0..7  (== XCD)
    const int bn = (int)blockIdx.y * BN;      // ntile 0..31

    const int tid  = threadIdx.x;
    const int lane = tid & 63;
    const int wave = tid >> 6;      // 0..7
    const int r15  = lane & 15;
    const int quad = lane >> 4;
    const int r7   = r15 & 7;
    const int wm   = wave >> 2;     // 0..1 : 128-row M half
    const int wn   = wave & 3;      // 0..3 : 48-col  N slice

    // Staging: one async_copy16 issue = 512 thr x 16B = 64 rows of 64 bf16.
    // lane -> row (lane>>3) within the wave's 8-row span, chunk (lane&7);
    // source chunk pre-XORed with row&7 (row mod 8 == (lane>>3)&7 since all
    // other row terms are multiples of 8).
    const int sr8 = lane >> 3;                 // 0..7
    const int sck = (lane & 7) ^ sr8;
    const __bf16* Ap = A  + (size_t)(bm + wave * 8 + sr8) * KD + sck * 8;
    const __bf16* Bp = Bf + (size_t)(bn + wave * 8 + sr8) * KD + sck * 8;

    auto stageA = [&](int buf, int kt) {       // 4 issues: 256 rows
        #pragma unroll
        for (int j = 0; j < 4; j++)
            async_copy16(Ap + (size_t)(j * 64) * KD + kt, &As[buf][j * 4096 + wave * 512]);
    };
    auto stageB = [&](int buf, int kt) {       // 3 issues: 192 rows
        #pragma unroll
        for (int j = 0; j < 3; j++)
            async_copy16(Bp + (size_t)(j * 64) * KD + kt, &Bs[buf][j * 4096 + wave * 512]);
    };

    f32x4 acc[8][3] = {};         // 96 VGPR
    bf16x8 a0[4][2], a1[4][2];    // 64 VGPR
    bf16x8 bE[3][2], bO[3][2];    // 48 VGPR

    auto tile_step = [&](int t, bf16x8 (&bc)[3][2], bf16x8 (&bnx)[3][2]) {
        const int b = t & 1;
        const __bf16* Asb = As[b];
        const __bf16* Aso = As[b ^ 1];
        const __bf16* Bso = Bs[b ^ 1];
        const bool pf = (t + 2 < NT);
        const bool rd = (t + 1 < NT);
        const int ktp = (t + 2) * BK;

        // ---- ph1: read a1(t); stage B(t+2); q1 = a0 x bc; drain; bar ----
        #pragma unroll
        for (int mf = 0; mf < 4; mf++)
            #pragma unroll
            for (int s = 0; s < 2; s++)
                a1[mf][s] = ld_frag(Asb, wm * 128 + 64 + mf * 16 + r15, s, quad, r7);
        if (pf) stageB(b, ktp);
        __builtin_amdgcn_sched_barrier(0);
        __builtin_amdgcn_s_setprio(1);
        #pragma unroll
        for (int mf = 0; mf < 4; mf++)
            #pragma unroll
            for (int nf = 0; nf < 3; nf++)
                #pragma unroll
                for (int s = 0; s < 2; s++)
                    acc[mf][nf] = __builtin_amdgcn_mfma_f32_16x16x32_bf16(a0[mf][s], bc[nf][s], acc[mf][nf], 0, 0, 0);
        __builtin_amdgcn_s_setprio(0);
        __builtin_amdgcn_sched_barrier(0);
        if (pf) asm volatile("s_waitcnt vmcnt(3)" ::: "memory");   // drain t+1, keep B(t+2)
        else    asm volatile("s_waitcnt vmcnt(0)" ::: "memory");   // tail
        __builtin_amdgcn_s_barrier();
        __builtin_amdgcn_sched_barrier(0);

        // ---- ph2: read b(t+1), a0(t+1); stage A(t+2); q2 = a1 x bc; bar ----
        if (rd) {
            #pragma unroll
            for (int nf = 0; nf < 3; nf++)
                #pragma unroll
                for (int s = 0; s < 2; s++)
                    bnx[nf][s] = ld_frag(Bso, wn * 48 + nf * 16 + r15, s, quad, r7);
            #pragma unroll
            for (int mf = 0; mf < 4; mf++)
                #pragma unroll
                for (int s = 0; s < 2; s++)
                    a0[mf][s] = ld_frag(Aso, wm * 128 + mf * 16 + r15, s, quad, r7);
        }
        if (pf) stageA(b, ktp);
        __builtin_amdgcn_sched_barrier(0);
        __builtin_amdgcn_s_setprio(1);
        #pragma unroll
        for (int mf = 0; mf < 4; mf++)
            #pragma unroll
            for (int nf = 0; nf < 3; nf++)
                #pragma unroll
                for (int s = 0; s < 2; s++)
                    acc[4 + mf][nf] = __builtin_amdgcn_mfma_f32_16x16x32_bf16(a1[mf][s], bc[nf][s], acc[4 + mf][nf], 0, 0, 0);
        __builtin_amdgcn_s_setprio(0);
        __builtin_amdgcn_sched_barrier(0);
        __builtin_amdgcn_s_barrier();
        __builtin_amdgcn_sched_barrier(0);
    };

    // ---- prologue: stage t0 -> buf0, t1 -> buf1; first operands ----
    stageB(0, 0);  stageA(0, 0);
    stageB(1, BK); stageA(1, BK);
    asm volatile("s_waitcnt vmcnt(7)" ::: "memory");   // t0 landed (7 ops), t1 in flight
    __builtin_amdgcn_s_barrier();
    __builtin_amdgcn_sched_barrier(0);
    #pragma unroll
    for (int nf = 0; nf < 3; nf++)
        #pragma unroll
        for (int s = 0; s < 2; s++)
            bE[nf][s] = ld_frag(Bs[0], wn * 48 + nf * 16 + r15, s, quad, r7);
    #pragma unroll
    for (int mf = 0; mf < 4; mf++)
        #pragma unroll
        for (int s = 0; s < 2; s++)
            a0[mf][s] = ld_frag(As[0], wm * 128 + mf * 16 + r15, s, quad, r7);

    for (int t = 0; t < NT; t += 2) {
        tile_step(t,     bE, bO);
        tile_step(t + 1, bO, bE);
    }

    // ---- epilogue: split fused N back into q/k/v matrices ----
    #pragma unroll
    for (int nf = 0; nf < 3; nf++) {
        const int col0 = bn + wn * 48 + nf * 16;          // 0..6143, mult of 16
        const int mat  = col0 >> 11;                      // 0..2
        const int colr = (col0 & 2047) + r15;
        __bf16* Cm = Cf + (size_t)mat * T_SEQ * D_MODEL;
        #pragma unroll
        for (int mf = 0; mf < 8; mf++) {
            #pragma unroll
            for (int r = 0; r < 4; r++) {
                const size_t row = (size_t)(bm + wm * 128 + mf * 16 + quad * 4 + r);
                Cm[row * D_MODEL + colr] = (__bf16)acc[mf][nf][r];
            }
        }
    }
}

// ---------------------------------------------------------------------------
// Projection GEMM: out = attn @ Wo^T, fp32 direct stores. 128x128 tile, BK=64,
// 256 threads (4 waves, 2x2), grid 16x16 = 256 blocks (full CU fill, XCD
// swizzle). v3 pipelined 4-phase schedule, reads 4/4/4/4 per phase.
// ---------------------------------------------------------------------------
__global__ __launch_bounds__(256) void proj_gemm_kernel(
    const __bf16* __restrict__ A, const __bf16* __restrict__ Bmat, float* __restrict__ C)
{
    constexpr int BM = 128, BK = 64, KD = D_MODEL, NT = KD / BK;   // 32 K-tiles

    __shared__ __align__(16) __bf16 As[2][BM * BK];   // 2 x 16 KB
    __shared__ __align__(16) __bf16 Bs[2][BM * BK];   // 2 x 16 KB

    // XCD swizzle over 256 blocks (256 % 8 == 0 -> bijective)
    const int flat = (int)blockIdx.x + 16 * (int)blockIdx.y;
    const int swz  = (flat & 7) * 32 + (flat >> 3);
    const int bm   = (swz & 15) * BM;
    const int bn   = (swz >> 4) * BM;

    const int tid  = threadIdx.x;
    const int lane = tid & 63;
    const int wave = tid >> 6;      // 0..3
    const int r15  = lane & 15;
    const int quad = lane >> 4;
    const int r7   = r15 & 7;
    const int wm   = (wave >> 1) * 64;
    const int wn   = (wave & 1) * 64;

    const int sr8 = lane >> 3;
    const int sck = (lane & 7) ^ sr8;
    const __bf16* Ap = A    + (size_t)(bm + wave * 8 + sr8) * KD + sck * 8;
    const __bf16* Bp = Bmat + (size_t)(bn + wave * 8 + sr8) * KD + sck * 8;

    auto stageA = [&](int buf, int kt) {
        #pragma unroll
        for (int j = 0; j < 4; j++)
            async_copy16(Ap + (size_t)(j * 32) * KD + kt, &As[buf][wave * 512 + j * 2048]);
    };
    auto stageB = [&](int buf, int kt) {
        #pragma unroll
        for (int j = 0; j < 4; j++)
            async_copy16(Bp + (size_t)(j * 32) * KD + kt, &Bs[buf][wave * 512 + j * 2048]);
    };

    f32x4 acc[4][4] = {};
    bf16x8 a0[2][2], a1[2][2], b0[2][2], b1[2][2];

    auto mfma8 = [&](int mb, int nb, bf16x8 (&av)[2][2], bf16x8 (&bv)[2][2]) {
        #pragma unroll
        for (int mf = 0; mf < 2; mf++)
            #pragma unroll
            for (int nf = 0; nf < 2; nf++)
                #pragma unroll
                for (int s = 0; s < 2; s++)
                    acc[mb + mf][nb + nf] =
                        __builtin_amdgcn_mfma_f32_16x16x32_bf16(av[mf][s], bv[nf][s], acc[mb + mf][nb + nf], 0, 0, 0);
    };

    // prologue: t0 -> buf0, t1 -> buf1
    stageB(0, 0);  stageA(0, 0);
    stageB(1, BK); stageA(1, BK);
    asm volatile("s_waitcnt vmcnt(8)" ::: "memory");
    __builtin_amdgcn_s_barrier();
    __builtin_amdgcn_sched_barrier(0);
    #pragma unroll
    for (int mf = 0; mf < 2; mf++)
        #pragma unroll
        for (int s = 0; s < 2; s++)
            a0[mf][s] = ld_frag(As[0], wm + mf * 16 + r15, s, quad, r7);
    #pragma unroll
    for (int nf = 0; nf < 2; nf++)
        #pragma unroll
        for (int s = 0; s < 2; s++)
            b0[nf][s] = ld_frag(Bs[0], wn + nf * 16 + r15, s, quad, r7);

    for (int t = 0; t < NT; t++) {
        const int b = t & 1;
        const __bf16* Asb = As[b];
        const __bf16* Bsb = Bs[b];
        const __bf16* Aso = As[b ^ 1];
        const __bf16* Bso = Bs[b ^ 1];
        const bool pf = (t + 2 < NT);
        const bool rd = (t + 1 < NT);
        const int ktp = (t + 2) * BK;

        // ph1: read b1(t); MFMA q1
        #pragma unroll
        for (int nf = 0; nf < 2; nf++)
            #pragma unroll
            for (int s = 0; s < 2; s++)
                b1[nf][s] = ld_frag(Bsb, wn + 32 + nf * 16 + r15, s, quad, r7);
        __builtin_amdgcn_sched_barrier(0);
        __builtin_amdgcn_s_setprio(1);
        mfma8(0, 0, a0, b0);
        __builtin_amdgcn_s_setprio(0);
        __builtin_amdgcn_sched_barrier(0);
        __builtin_amdgcn_s_barrier();
        __builtin_amdgcn_sched_barrier(0);

        // ph2: stage B(t+2); read a1(t); MFMA q2; drain t+1
        if (pf) stageB(b, ktp);
        #pragma unroll
        for (int mf = 0; mf < 2; mf++)
            #pragma unroll
            for (int s = 0; s < 2; s++)
                a1[mf][s] = ld_frag(Asb, wm + 32 + mf * 16 + r15, s, quad, r7);
        __builtin_amdgcn_sched_barrier(0);
        __builtin_amdgcn_s_setprio(1);
        mfma8(0, 2, a0, b1);
        __builtin_amdgcn_s_setprio(0);
        __builtin_amdgcn_sched_barrier(0);
        if (pf) asm volatile("s_waitcnt vmcnt(4)" ::: "memory");
        else    asm volatile("s_waitcnt vmcnt(0)" ::: "memory");
        __builtin_amdgcn_s_barrier();
        __builtin_amdgcn_sched_barrier(0);

        // ph3: read a0(t+1); stage A(t+2); MFMA q3
        if (rd)
            #pragma unroll
            for (int mf = 0; mf < 2; mf++)
                #pragma unroll
                for (int s = 0; s < 2; s++)
                    a0[mf][s] = ld_frag(Aso, wm + mf * 16 + r15, s, quad, r7);
        if (pf) stageA(b, ktp);
        __builtin_amdgcn_sched_barrier(0);
        __builtin_amdgcn_s_setprio(1);
        mfma8(2, 2, a1, b1);
        __builtin_amdgcn_s_setprio(0);
        __builtin_amdgcn_sched_barrier(0);
        __builtin_amdgcn_s_barrier();
        __builtin_amdgcn_sched_barrier(0);

        // ph4: MFMA q4 (old b0); read b0(t+1)
        __builtin_amdgcn_s_setprio(1);
        mfma8(2, 0, a1, b0);
        __builtin_amdgcn_s_setprio(0);
        __builtin_amdgcn_sched_barrier(0);
        if (rd)
            #pragma unroll
            for (int nf = 0; nf < 2; nf++)
                #pragma unroll
                for (int s = 0; s < 2; s++)
                    b0[nf][s] = ld_frag(Bso, wn + nf * 16 + r15, s, quad, r7);
        __builtin_amdgcn_sched_barrier(0);
        __builtin_amdgcn_s_barrier();
        __builtin_amdgcn_sched_barrier(0);
    }

    // epilogue: fp32 direct stores (each output element written exactly once)
    #pragma unroll
    for (int mf = 0; mf < 4; mf++) {
        #pragma unroll
        for (int r = 0; r < 4; r++) {
            const size_t row = (size_t)(bm + wm + mf * 16 + quad * 4 + r);
            #pragma unroll
            for (int nf = 0; nf < 4; nf++) {
                const size_t col = (size_t)(bn + wn + nf * 16 + r15);
                C[row * D_MODEL + col] = acc[mf][nf][r];
            }
        }
    }
}

// ---------------------------------------------------------------------------
// Preproc q/k: conv(K=4)+SiLU+RMSNorm+RoPE, pure-register.
// q pre-scaled by 1/sqrt(HD); outer rotary negation dropped (cancels in qk^T).
// ---------------------------------------------------------------------------
__global__ __launch_bounds__(256) void preproc_qk_kernel(
    const __bf16* __restrict__ q_raw, const __bf16* __restrict__ k_raw,
    const float* __restrict__ cwq, const float* __restrict__ cwk,
    const float* __restrict__ qnw, const float* __restrict__ knw,
    const float* __restrict__ cosb, const float* __restrict__ sinb,
    __bf16* __restrict__ q_proc, __bf16* __restrict__ k_proc)
{
    const int t = blockIdx.x;
    const int which = blockIdx.y;
    const __bf16* X = which ? k_raw : q_raw;
    const float*  W = which ? cwk : cwq;
    const float*  nw = which ? knw : qnw;
    __bf16* P = which ? k_proc : q_proc;
    const float SC = which ? 1.0f : 0.08838834764831845f;  // 1/sqrt(128) folded into q

    const int tid = threadIdx.x;
    const int c0  = tid * 8;
    const int h   = tid >> 4;
    const int dl0 = (tid & 15) * 8;

    f32x4 wv[8];
    #pragma unroll
    for (int i = 0; i < 8; i++) wv[i] = *(const f32x4*)&W[(c0 + i) * 4];

    float acc[8] = {};
    #pragma unroll
    for (int j = 0; j < 4; j++) {
        int tt = t + j - 3;
        if (tt >= 0) {
            bf16x8 xv = *(const bf16x8*)&X[(size_t)tt * D_MODEL + c0];
            #pragma unroll
            for (int i = 0; i < 8; i++) acc[i] += (float)xv[i] * wv[i][j];
        }
    }
    float sil[8], ss = 0.f;
    #pragma unroll
    for (int i = 0; i < 8; i++) {
        float s = acc[i] / (1.f + __expf(-acc[i]));
        sil[i] = s; ss += s * s;
    }
    #pragma unroll
    for (int off = 1; off < 16; off <<= 1) ss += __shfl_xor(ss, off);
    float inv = rsqrtf(ss * (1.f / 128.f) + 1e-5f);

    f32x4 nv0 = *(const f32x4*)&nw[dl0];
    f32x4 nv1 = *(const f32x4*)&nw[dl0 + 4];
    float yn[8];
    #pragma unroll
    for (int i = 0; i < 8; i++) yn[i] = sil[i] * inv * (i < 4 ? nv0[i] : nv1[i - 4]);

    float partner[8];
    #pragma unroll
    for (int i = 0; i < 8; i++) partner[i] = __shfl_xor(yn[i], 4);  // dl ^ 32

    bf16x8 o;
    if (dl0 < RD_ROT) {
        f32x4 cv0 = *(const f32x4*)&cosb[t * RD_ROT + dl0];
        f32x4 cv1 = *(const f32x4*)&cosb[t * RD_ROT + dl0 + 4];
        f32x4 sv0 = *(const f32x4*)&sinb[t * RD_ROT + dl0];
        f32x4 sv1 = *(const f32x4*)&sinb[t * RD_ROT + dl0 + 4];
        #pragma unroll
        for (int i = 0; i < 8; i++) {
            int dl = dl0 + i;
            float c = i < 4 ? cv0[i] : cv1[i - 4];
            float s = i < 4 ? sv0[i] : sv1[i - 4];
            float rot = (dl < 32) ? -partner[i] : partner[i];  // rotate_half
            o[i] = (__bf16)((yn[i] * c + rot * s) * SC);
        }
    } else {
        #pragma unroll
        for (int i = 0; i < 8; i++) o[i] = (__bf16)(yn[i] * SC);
    }
    *(bf16x8*)&P[((size_t)h * T_SEQ + t) * HDIM + dl0] = o;
}

// ---------------------------------------------------------------------------
// Preproc v: conv+SiLU, transposed (H, HD, T) store, bf16x8 per thread.
// ---------------------------------------------------------------------------
__global__ __launch_bounds__(128) void preproc_v_kernel(
    const __bf16* __restrict__ v_raw, const float* __restrict__ cwv,
    __bf16* __restrict__ v_t)
{
    const int t0 = blockIdx.x * 8;
    const int h = blockIdx.y;
    const int dl = threadIdx.x;
    const int d = h * HDIM + dl;

    f32x4 wv = *(const f32x4*)&cwv[d * 4];
    float x[11];
    #pragma unroll
    for (int m = 0; m < 11; m++) {
        int tt = t0 - 3 + m;
        x[m] = (tt >= 0) ? (float)v_raw[(size_t)tt * D_MODEL + d] : 0.f;
    }
    bf16x8 o;
    #pragma unroll
    for (int r = 0; r < 8; r++) {
        float y = x[r] * wv[0] + x[r + 1] * wv[1] + x[r + 2] * wv[2] + x[r + 3] * wv[3];
        o[r] = (__bf16)(y / (1.f + __expf(-y)));
    }
    *(bf16x8*)&v_t[((size_t)h * HDIM + dl) * T_SEQ + t0] = o;
}

// ---------------------------------------------------------------------------
// Flash attention, causal — 4 waves x 16 q-rows, STATIC-MAX softmax,
// raw s_barrier + counted vmcnt, 2-deep staging (R4, verified).
// ---------------------------------------------------------------------------
__global__ __launch_bounds__(256, 2) void attn_kernel(
    const __bf16* __restrict__ Qp,   // (H, T, HD), pre-scaled
    const __bf16* __restrict__ Kp,   // (H, T, HD)
    const __bf16* __restrict__ Vt,   // (H, HD, T)
    __bf16* __restrict__ Op)         // (T, D)
{
    constexpr int TK = 64, PSTR = 72;
    __shared__ __align__(16) __bf16 Ks[2][TK * HDIM];   // 2 x 16 KB
    __shared__ __align__(16) __bf16 Vs[2][HDIM * TK];   // 2 x 16 KB
    __shared__ __align__(16) __bf16 Ps[64 * PSTR];      // 9 KB

    const int lane = threadIdx.x & 63;
    const int wave = threadIdx.x >> 6;
    const int r15  = lane & 15;
    const int quad = lane >> 4;
    const int h = blockIdx.y;
    const int qi = (blockIdx.y & 8) ? ((int)gridDim.x - 1 - (int)blockIdx.x) : (int)blockIdx.x;
    const int q0 = qi * TK;

    const __bf16* Kb = Kp + (size_t)h * T_SEQ * HDIM;
    const __bf16* Vb = Vt + (size_t)h * HDIM * T_SEQ;

    const int kchunk = wave * 4;
    const int krow_l = (lane >> 4);
    const int kg     = lane & 15;
    const int vrow_l = (lane >> 3);
    const int vg     = lane & 7;

    auto stage_tile = [&](int tile, int sb) {
        const int tkn = tile * TK;
        #pragma unroll
        for (int i = 0; i < 4; i++) {
            int ck = kchunk + i;
            int krow = ck * 4 + krow_l;
            int vrow = ck * 8 + vrow_l;
            async_copy16(Kb + (size_t)(tkn + krow) * HDIM + (kg ^ (krow & 15)) * 8, &Ks[sb][ck * 512]);
            async_copy16(Vb + (size_t)vrow * T_SEQ + tkn + (vg ^ (vrow & 7)) * 8, &Vs[sb][ck * 512]);
        }
    };

    bf16x8 qf[4];
    const __bf16* qbase = Qp + ((size_t)h * T_SEQ + q0 + wave * 16 + r15) * HDIM;
    #pragma unroll
    for (int s = 0; s < 4; s++) qf[s] = *(const bf16x8*)(qbase + s * 32 + quad * 8);

    f32x4 oacc[8] = {};
    float lsum[4] = {};

    const int ntk = qi + 1;

    // ---- prologue: 2-deep staging ----
    stage_tile(0, 0);
    if (ntk > 1) stage_tile(1, 1);

    for (int it = 0; it < ntk; it++) {
        const int buf = it & 1;
        const bool last = (it == ntk - 1);

        if (last) asm volatile("s_waitcnt vmcnt(0)" ::: "memory");   // only stage(it) left
        else      asm volatile("s_waitcnt vmcnt(8)" ::: "memory");   // drain it, keep it+1 flying
        __builtin_amdgcn_s_barrier();

        // ---- S = Q K^T ----
        f32x4 sacc[4] = {};
        #pragma unroll
        for (int s = 0; s < 4; s++) {
            #pragma unroll
            for (int nt = 0; nt < 4; nt++) {
                bf16x8 kf = *(const bf16x8*)&Ks[buf][(nt * 16 + r15) * HDIM + (((s * 4 + quad) ^ r15) << 3)];
                sacc[nt] = __builtin_amdgcn_mfma_f32_16x16x32_bf16(qf[s], kf, sacc[nt], 0, 0, 0);
            }
        }

        // ---- p = exp(s), static max; mask only on the diagonal tile ----
        #pragma unroll
        for (int nt = 0; nt < 4; nt++) {
            #pragma unroll
            for (int r = 0; r < 4; r++) {
                float p = __expf(sacc[nt][r]);
                if (last) {
                    int qrow = q0 + wave * 16 + quad * 4 + r;
                    int kcol = it * TK + nt * 16 + r15;
                    if (kcol > qrow) p = 0.f;
                }
                sacc[nt][r] = p;
                lsum[r] += p;
            }
        }

        // ---- P: C-layout -> LDS (wave-private rows, no barrier) ----
        #pragma unroll
        for (int nt = 0; nt < 4; nt++)
            #pragma unroll
            for (int r = 0; r < 4; r++)
                Ps[(wave * 16 + quad * 4 + r) * PSTR + nt * 16 + r15] = (__bf16)sacc[nt][r];

        // ---- O += P V ----
        #pragma unroll
        for (int s2 = 0; s2 < 2; s2++) {
            bf16x8 pf = *(const bf16x8*)&Ps[(wave * 16 + r15) * PSTR + s2 * 32 + quad * 8];
            #pragma unroll
            for (int nt = 0; nt < 8; nt++) {
                bf16x8 vf = *(const bf16x8*)&Vs[buf][(nt * 16 + r15) * TK + (((s2 * 4 + quad) ^ (r15 & 7)) << 3)];
                oacc[nt] = __builtin_amdgcn_mfma_f32_16x16x32_bf16(pf, vf, oacc[nt], 0, 0, 0);
            }
        }

        // ---- post-compute barrier, then stage it+2 into this buf ----
        __builtin_amdgcn_s_barrier();
        if (it + 2 < ntk) stage_tile(it + 2, buf);
    }

    #pragma unroll
    for (int r = 0; r < 4; r++) {
        float l = lsum[r];
        #pragma unroll
        for (int off = 1; off < 16; off <<= 1) l += __shfl_xor(l, off);
        float inv = 1.0f / l;
        size_t row = q0 + wave * 16 + quad * 4 + r;
        #pragma unroll
        for (int nt = 0; nt < 8; nt++)
            Op[row * D_MODEL + h * HDIM + nt * 16 + r15] = (__bf16)(oacc[nt][r] * inv);
    }
}

// ---------------------------------------------------------------------------
extern "C" void kernel_launch(void* const* d_in, const int* in_sizes, int n_in,
                              void* d_out, int out_size, void* d_ws, size_t ws_size,
                              hipStream_t stream) {
    (void)in_sizes; (void)n_in; (void)out_size; (void)ws_size;
    const float* hidden = (const float*)d_in[0];
    const float* cosb   = (const float*)d_in[1];
    const float* sinb   = (const float*)d_in[2];
    const float* Wq     = (const float*)d_in[3];
    const float* Wk     = (const float*)d_in[4];
    const float* Wv     = (const float*)d_in[5];
    const float* Wo     = (const float*)d_in[6];
    const float* cwq    = (const float*)d_in[7];
    const float* cwk    = (const float*)d_in[8];
    const float* cwv    = (const float*)d_in[9];
    const float* qnw    = (const float*)d_in[10];
    const float* knw    = (const float*)d_in[11];

    const size_t NEL = (size_t)T_SEQ * D_MODEL;
    __bf16* ws = (__bf16*)d_ws;
    __bf16* h_bf   = ws + 0 * NEL;   // later reused as attn_b
    __bf16* Wq_bf  = ws + 1 * NEL;   // Wq;Wk;Wv contiguous = fused B (6144x2048)
    __bf16* Wk_bf  = ws + 2 * NEL;
    __bf16* Wv_bf  = ws + 3 * NEL;
    __bf16* Wo_bf  = ws + 4 * NEL;   // persists to final GEMM
    __bf16* q_raw  = ws + 5 * NEL;   // q;k;v contiguous = fused C
    __bf16* k_raw  = ws + 6 * NEL;
    __bf16* v_raw  = ws + 7 * NEL;
    __bf16* q_proc = Wq_bf;          // reuse after GEMM
    __bf16* k_proc = Wk_bf;
    __bf16* v_t    = Wv_bf;
    __bf16* attn_b = h_bf;
    float*  out    = (float*)d_out;

    // 0. cast fp32 inputs to bf16
    cast_kernel<<<dim3(T_SEQ, 5), 256, 0, stream>>>(hidden, Wq, Wk, Wv, Wo,
                                                    h_bf, Wq_bf, Wk_bf, Wv_bf, Wo_bf);
    // 1. fused QKV GEMM: (2048x2048) @ (6144x2048)^T — 256x192 tiles,
    //    grid 8x32 = 256 blocks = exactly 1/CU
    gemm_qkv_fused_kernel<<<dim3(8, 32), 512, 0, stream>>>(h_bf, Wq_bf, q_raw);
    // 2. preproc
    preproc_qk_kernel<<<dim3(T_SEQ, 2), 256, 0, stream>>>(
        q_raw, k_raw, cwq, cwk, qnw, knw, cosb, sinb, q_proc, k_proc);
    preproc_v_kernel<<<dim3(T_SEQ / 8, NH), 128, 0, stream>>>(v_raw, cwv, v_t);
    // 3. causal flash attention — raw barriers + counted vmcnt, 2-deep staging
    attn_kernel<<<dim3(T_SEQ / 64, NH), 256, 0, stream>>>(q_proc, k_proc, v_t, attn_b);
    // 4. out = attn @ Wo^T — 128x128 pipelined, 256 blocks, fp32 direct stores
    proj_gemm_kernel<<<dim3(16, 16), 256, 0, stream>>>(attn_b, Wo_bf, out);
}